// Round 3
// baseline (8166.331 us; speedup 1.0000x reference)
//
#include <hip/hip_runtime.h>
#include <hip/hip_bf16.h>

// GCLSTM: B=512, T=32, H=300, K=10 neighbors. Inputs AND output are float32
// (R1/R2 evidence: bf16-decoding inputs produces NaN => inputs are f32;
// R1's 3.69 absmax == labels-bits aliasing into the f32-read preds region
// => output buffer is f32).
// Two-pass design forced by the flat-reshape softmax scramble:
//   kernA: cells -> wp-proj -> con1 -> fc1 -> wdyn -> softmax -> sm[t][k][b]
//   kernB: (recompute con1) -> gather wa3 -> cat -> fuse/fusiondis -> preds
// kprep pre-transposes weights for coalesced access. kernC writes labels_r.

#define TB 4
#define NTHR 320
#define CH 50

// ws layout (float offsets)
#define OFF_SM    0         // [32][10][512]            163840
#define OFF_WPT   163840    // wpT[h<600][o<300]        180000
#define OFF_WIHP  343840    // ((k*11+i)*3+g)*300+h      99000
#define OFF_BCP   442840    // (k*3+g)*300+h              9000
#define OFF_BTP   451840    // g*300+h                     900
#define OFF_WTP   452740    // (e*3+g)*300+h              3600
#define OFF_WA    456340    // softmax(DisM)                10
#define OFF_SWA   456350    // sum(wA)                       1
#define OFF_F1P   456352    // u32 view: [(h*64+lane)*2+q]  76800 u32
#define WS_MIN_BYTES ((size_t)(456352 + 76800) * 4)

__device__ __forceinline__ float sigf(float x){ return 1.0f/(1.0f+__expf(-x)); }
__device__ __forceinline__ float tanhf_(float x){ return 1.0f - 2.0f/(__expf(2.0f*x)+1.0f); }
__device__ __forceinline__ float blo(unsigned u){ return __uint_as_float(u<<16); }
__device__ __forceinline__ float bhi(unsigned u){ return __uint_as_float(u&0xffff0000u); }
__device__ __forceinline__ unsigned short f2us(float f){ return (unsigned short)(__float_as_uint(f)>>16); }

// Builds con1 (bf16, [TB][300][12] LDS) for this (t, b-tile).
// t==0: con1 = cells(x[0]) directly (no wp, no relu). t>0: relu(wp·[con_t;con_{t-1}]+bp).
__device__ void build_con1(const float* __restrict__ li, const float* __restrict__ wsf,
                           const float* __restrict__ bp, int t, int b0,
                           float (*xs)[11][10], float (*ccs)[CH][12],
                           unsigned short (*con1s)[300][12])
{
  const int tid = threadIdx.x;
  float acc[TB][10];
  #pragma unroll
  for (int b=0;b<TB;b++)
    #pragma unroll
    for (int k=0;k<10;k++) acc[b][k]=0.f;
  const int nchunk = (t==0)?6:12;
  for (int c=0;c<nchunk;c++){
    const int tp = (c<6)? t : (t-1);
    const int h0 = (c<6)? c*CH : (c-6)*CH;
    if (c==0 || c==6){
      for (int p=tid; p<TB*110; p+=NTHR){
        int b=p/110, r=p%110, i=r/10, k=r%10;
        xs[b][i][k] = li[(((b0+b)*32 + tp)*28 + i)*10 + k];
      }
    }
    __syncthreads();   // xs staged; also guards ccs overwrite vs prev chunk's wp reads
    for (int p=tid; p<10*CH; p+=NTHR){
      int k=p/CH, hr=p%CH, h=h0+hr;
      float ai[TB], ag[TB], ao[TB];
      #pragma unroll
      for (int b=0;b<TB;b++){ ai[b]=0.f; ag[b]=0.f; ao[b]=0.f; }
      const float* W = wsf + OFF_WIHP + k*9900 + h;
      #pragma unroll
      for (int i=0;i<11;i++){
        float wi = W[(i*3+0)*300];
        float wg = W[(i*3+1)*300];
        float wo = W[(i*3+2)*300];
        #pragma unroll
        for (int b=0;b<TB;b++){
          float xv = xs[b][i][k];
          ai[b] += wi*xv; ag[b] += wg*xv; ao[b] += wo*xv;
        }
      }
      float bi = wsf[OFF_BCP + (k*3+0)*300 + h];
      float bg2= wsf[OFF_BCP + (k*3+1)*300 + h];
      float bo = wsf[OFF_BCP + (k*3+2)*300 + h];
      #pragma unroll
      for (int b=0;b<TB;b++){
        float hv = sigf(ao[b]+bo) * tanhf_( sigf(ai[b]+bi) * tanhf_(ag[b]+bg2) );
        if (t==0) con1s[b][h][k] = f2us(hv);   // con0 used raw by attend
        else      ccs[b][hr][k] = hv;
      }
    }
    __syncthreads();
    if (t>0 && tid<300){
      const int o = tid;
      const float* wrow = wsf + OFF_WPT + (c*CH)*300 + o;
      for (int hr=0;hr<CH;hr++){
        float w = wrow[hr*300];          // coalesced across o-lanes
        #pragma unroll
        for (int b=0;b<TB;b++){
          const float4* r4 = (const float4*)(&ccs[b][hr][0]); // 48B rows, 16B aligned
          float4 v0 = r4[0]; float4 v1 = r4[1]; float4 v2 = r4[2];
          acc[b][0] += w*v0.x; acc[b][1] += w*v0.y; acc[b][2] += w*v0.z; acc[b][3] += w*v0.w;
          acc[b][4] += w*v1.x; acc[b][5] += w*v1.y; acc[b][6] += w*v1.z; acc[b][7] += w*v1.w;
          acc[b][8] += w*v2.x; acc[b][9] += w*v2.y;  // cols 10,11 are pad, never used
        }
      }
    }
  }
  if (t>0 && tid<300){
    const int o = tid;
    float bpv = bp[o];
    #pragma unroll
    for (int b=0;b<TB;b++)
      #pragma unroll
      for (int k=0;k<10;k++){
        float v = acc[b][k] + bpv;
        con1s[b][o][k] = f2us(v>0.f? v : 0.f);
      }
  }
  __syncthreads();
}

__global__ __launch_bounds__(NTHR,2) void kernA(
    const float* __restrict__ li, const float* __restrict__ exs,
    const float* __restrict__ AngleM, const float* __restrict__ bp,
    const float* __restrict__ b1, const float* __restrict__ F2,
    const float* __restrict__ b2, float* __restrict__ wsf)
{
  __shared__ float xs[TB][11][10];
  __shared__ __align__(16) float ccs[TB][CH][12];
  __shared__ __align__(8) unsigned short con1s[TB][300][12];
  __shared__ float hts[TB][300];
  __shared__ float xse[TB][2][10];   // x rows 8, 10 of x[t]
  __shared__ float exss[TB][4];
  const int tid = threadIdx.x;
  const int t = blockIdx.y;
  const int b0 = blockIdx.x*TB;

  for (int p=tid;p<TB*20;p+=NTHR){
    int b=p/20, r=p%20, rr=r/10, k=r%10;
    xse[b][rr][k] = li[(((b0+b)*32+t)*28 + (rr?10:8))*10 + k];
  }
  for (int p=tid;p<TB*4;p+=NTHR){
    int b=p/4, e=p%4;
    exss[b][e] = exs[((b0+b)*32+t)*4 + e];
  }
  __syncthreads();
  // target_cell -> hts
  for (int p=tid;p<TB*300;p+=NTHR){
    int b=p/300, h=p%300;
    float ai=0.f, ag=0.f, ao=0.f;
    #pragma unroll
    for (int e=0;e<4;e++){
      float xv = exss[b][e];
      ai += wsf[OFF_WTP+(e*3+0)*300+h]*xv;
      ag += wsf[OFF_WTP+(e*3+1)*300+h]*xv;
      ao += wsf[OFF_WTP+(e*3+2)*300+h]*xv;
    }
    ai += wsf[OFF_BTP+h]; ag += wsf[OFF_BTP+300+h]; ao += wsf[OFF_BTP+600+h];
    hts[b][h] = sigf(ao)*tanhf_(sigf(ai)*tanhf_(ag));
  }
  build_con1(li, wsf, bp, t, b0, xs, ccs, con1s);

  const int w = tid>>6, lane = tid&63;
  if (w < TB){   // wave <-> b; lane j-tiling jj*64+lane, all 10 k in registers
    const int b = w, bg = b0+b;
    const unsigned* F1P = (const unsigned*)wsf + OFF_F1P;
    float hb[4];
    #pragma unroll
    for (int jj=0;jj<4;jj++){ int j=jj*64+lane; hb[jj] = (j<200)? b1[j] : 0.f; }
    for (int h=0;h<300;h++){  // htarget @ F1[300:600] (shared across k)
      float hv = hts[b][h];
      uint2 pp = *(const uint2*)(F1P + ((300+h)*64 + lane)*2);
      hb[0] += blo(pp.x)*hv; hb[1] += bhi(pp.x)*hv;
      hb[2] += blo(pp.y)*hv; hb[3] += bhi(pp.y)*hv;
    }
    float f2v[4];
    #pragma unroll
    for (int jj=0;jj<4;jj++){ int j=jj*64+lane; f2v[jj] = (j<200)? F2[j] : 0.f; }
    float acc[4][10];
    #pragma unroll
    for (int jj=0;jj<4;jj++)
      #pragma unroll
      for (int k=0;k<10;k++) acc[jj][k] = hb[jj];
    for (int h=0;h<300;h++){
      uint2 d0 = *(const uint2*)(&con1s[b][h][0]);
      uint2 d1 = *(const uint2*)(&con1s[b][h][4]);
      unsigned d2 = *(const unsigned*)(&con1s[b][h][8]);
      float cv[10];
      cv[0]=blo(d0.x); cv[1]=bhi(d0.x); cv[2]=blo(d0.y); cv[3]=bhi(d0.y);
      cv[4]=blo(d1.x); cv[5]=bhi(d1.x); cv[6]=blo(d1.y); cv[7]=bhi(d1.y);
      cv[8]=blo(d2);   cv[9]=bhi(d2);
      uint2 pp = *(const uint2*)(F1P + (h*64+lane)*2);
      float a0=blo(pp.x), a1=bhi(pp.x), a2=blo(pp.y), a3=bhi(pp.y);
      #pragma unroll
      for (int k=0;k<10;k++){
        float c = cv[k];
        acc[0][k] += a0*c; acc[1][k] += a1*c; acc[2][k] += a2*c; acc[3][k] += a3*c;
      }
    }
    float f2s8 = F2[200], f2ang = F2[201], b2v = b2[0];
    float wd[10];
    #pragma unroll
    for (int k=0;k<10;k++){
      float part = fmaxf(acc[0][k],0.f)*f2v[0] + fmaxf(acc[1][k],0.f)*f2v[1]
                 + fmaxf(acc[2][k],0.f)*f2v[2] + fmaxf(acc[3][k],0.f)*f2v[3];
      #pragma unroll
      for (int off=32;off>=1;off>>=1) part += __shfl_xor(part,off,64);
      float angv = fabsf(xse[b][1][k] - AngleM[k]) * (1.0f/360.0f);
      float v = part + xse[b][0][k]*f2s8 + angv*f2ang + b2v;
      wd[k] = fmaxf(v,0.f);
    }
    if (lane==0){  // stable softmax over k, write sm[t][k][bg]
      float m = wd[0];
      #pragma unroll
      for (int k=1;k<10;k++) m = fmaxf(m, wd[k]);
      float e[10]; float s=0.f;
      #pragma unroll
      for (int k=0;k<10;k++){ e[k] = __expf(wd[k]-m); s += e[k]; }
      float inv = 1.0f/s;
      float* smp = wsf + OFF_SM + t*5120 + bg;
      #pragma unroll
      for (int k=0;k<10;k++) smp[k*512] = e[k]*inv;
    }
  }
}

__global__ __launch_bounds__(NTHR,2) void kernB(
    const float* __restrict__ li, const float* __restrict__ bp,
    const float* __restrict__ ff, const float* __restrict__ bff,
    const float* __restrict__ fuse1, const float* __restrict__ biasf,
    const float* __restrict__ Wout, const float* __restrict__ biasout,
    const float* __restrict__ a, float* __restrict__ wsf,
    float* __restrict__ outp)
{
  __shared__ float xs[TB][11][10];
  __shared__ __align__(16) float ccs[TB][CH][12];
  __shared__ __align__(8) unsigned short con1s[TB][300][12];
  __shared__ float xs17[TB][17][10];
  __shared__ float cats[TB][300];
  __shared__ float wa3s[TB][10];
  __shared__ float dss[TB][17];
  __shared__ float wAs[10];
  const int tid = threadIdx.x;
  const int t = blockIdx.y;
  const int b0 = blockIdx.x*TB;
  for (int p=tid;p<TB*170;p+=NTHR){
    int b=p/170, r=p%170, f=r/10, k=r%10;
    xs17[b][f][k] = li[(((b0+b)*32+t)*28 + 11+f)*10 + k];
  }
  if (tid<10) wAs[tid] = wsf[OFF_WA+tid];
  build_con1(li, wsf, bp, t, b0, xs, ccs, con1s);
  // scrambled softmax gather: wa3[b][k] = smflat[(b*10+k)] of the [10,512] matrix
  for (int p=tid;p<TB*10;p+=NTHR){
    int b=p/10, k=p%10;
    int g = (b0+b)*10+k;
    wa3s[b][k] = wsf[OFF_SM + t*5120 + (g>>9)*512 + (g&511)];
  }
  for (int p=tid;p<TB*17;p+=NTHR){
    int b=p/17, f=p%17; float s=0.f;
    #pragma unroll
    for (int k=0;k<10;k++) s += xs17[b][f][k]*wAs[k];
    dss[b][f]=s;
  }
  __syncthreads();
  for (int p=tid;p<TB*300;p+=NTHR){
    int b=p/300, h=p%300;
    uint2 d0 = *(const uint2*)(&con1s[b][h][0]);
    uint2 d1 = *(const uint2*)(&con1s[b][h][4]);
    unsigned d2 = *(const unsigned*)(&con1s[b][h][8]);
    float s = blo(d0.x)*wa3s[b][0] + bhi(d0.x)*wa3s[b][1]
            + blo(d0.y)*wa3s[b][2] + bhi(d0.y)*wa3s[b][3]
            + blo(d1.x)*wa3s[b][4] + bhi(d1.x)*wa3s[b][5]
            + blo(d1.y)*wa3s[b][6] + bhi(d1.y)*wa3s[b][7]
            + blo(d2)*wa3s[b][8]   + bhi(d2)*wa3s[b][9];
    cats[b][h]=s;
  }
  __syncthreads();
  const int w = tid>>6, lane = tid&63;
  if (w<TB){
    const int b=w, bg=b0+b;
    const float aa = a[0], swa = wsf[OFF_SWA];
    const int o1 = lane;
    const bool o2v = lane<36;
    const int o2 = o2v ? (64+lane) : 99;
    float fu1 = biasf[o1], fu2 = biasf[o2];
    for (int h=0;h<300;h++){
      float cv = cats[b][h];
      fu1 += cv*fuse1[h*100+o1];
      fu2 += cv*fuse1[h*100+o2];
    }
    float fd1 = bff[o1]*swa, fd2 = bff[o2]*swa;
    #pragma unroll
    for (int f=0;f<17;f++){
      float dv = dss[b][f];
      fd1 += ff[o1*17+f]*dv;
      fd2 += ff[o2*17+f]*dv;
    }
    float v = (aa*fu1+(1.f-aa)*fd1)*Wout[o1];
    if (o2v) v += (aa*fu2+(1.f-aa)*fd2)*Wout[o2];
    #pragma unroll
    for (int off=32;off>=1;off>>=1) v += __shfl_xor(v,off,64);
    if (lane==0) outp[t*512+bg] = v + biasout[0];
  }
}

__global__ void kernC(const float* __restrict__ labels, float* __restrict__ outp){
  int p = blockIdx.x*256 + threadIdx.x;
  if (p < 16384){
    int t=p>>9, b=p&511;
    outp[16384+p] = labels[b*32+t];   // exact f32 copy (labels transpose)
  }
}

__global__ void kprep(const float* __restrict__ Wih, const float* __restrict__ b_ih,
                      const float* __restrict__ b_hh, const float* __restrict__ Wt,
                      const float* __restrict__ bt_ih, const float* __restrict__ bt_hh,
                      const float* __restrict__ wp, const float* __restrict__ F1,
                      float* __restrict__ wsf)
{
  int n = blockIdx.x*256 + threadIdx.x;
  if (n < 180000){ int h=n/300, o=n%300; wsf[OFF_WPT+n] = wp[o*600+h]; return; }
  n -= 180000;
  if (n < 99000){
    int h=n%300; int q=n/300; int g=q%3; int m=q/3; int i=m%11; int k=m/11;
    int G = h + (g==0?0:(g==1?600:900));
    wsf[OFF_WIHP+n] = Wih[(k*1200 + G)*11 + i]; return;
  }
  n -= 99000;
  if (n < 9000){
    int h=n%300; int q=n/300; int g=q%3, k=q/3;
    int G = h + (g==0?0:(g==1?600:900));
    wsf[OFF_BCP+n] = b_ih[k*1200+G] + b_hh[k*1200+G]; return;
  }
  n -= 9000;
  if (n < 900){
    int h=n%300, g=n/300;
    int G = h + (g==0?0:(g==1?600:900));
    wsf[OFF_BTP+n] = bt_ih[G]+bt_hh[G]; return;
  }
  n -= 900;
  if (n < 3600){
    int h=n%300; int q=n/300; int g=q%3, e=q/3;
    int G = h + (g==0?0:(g==1?600:900));
    wsf[OFF_WTP+n] = Wt[G*4+e]; return;
  }
  n -= 3600;
  if (n < 76800){   // F1 packed bf16x2: lane j-tiles {lane, 64+lane, 128+lane, 192+lane}
    int q=n%2; int r=n/2; int lane=r%64; int h=r/64;
    int j0 = q*128 + lane, j1 = q*128 + 64 + lane;
    float v0 = (j0<200)? F1[h*200+j0] : 0.f;
    float v1 = (j1<200)? F1[h*200+j1] : 0.f;
    unsigned u = (__float_as_uint(v1)&0xffff0000u) | (__float_as_uint(v0)>>16);
    ((unsigned*)wsf)[OFF_F1P + n] = u; return;
  }
}

__global__ void kprep2(const float* __restrict__ DisM, float* __restrict__ wsf){
  if (threadIdx.x==0 && blockIdx.x==0){
    float m = DisM[0];
    for (int k=1;k<10;k++) m = fmaxf(m, DisM[k]);
    float e[10]; float s=0.f;
    for (int k=0;k<10;k++){ e[k]=__expf(DisM[k]-m); s+=e[k]; }
    float inv=1.0f/s; float sw=0.f;
    for (int k=0;k<10;k++){ float v=e[k]*inv; wsf[OFF_WA+k]=v; sw+=v; }
    wsf[OFF_SWA]=sw;
  }
}

extern "C" void kernel_launch(void* const* d_in, const int* in_sizes, int n_in,
                              void* d_out, int out_size, void* d_ws, size_t ws_size,
                              hipStream_t stream)
{
  const float* li     = (const float*)d_in[0];
  const float* labels = (const float*)d_in[1];
  const float* exs    = (const float*)d_in[2];
  const float* DisM   = (const float*)d_in[3];
  const float* AngleM = (const float*)d_in[4];
  const float* Wih    = (const float*)d_in[5];
  const float* b_ih   = (const float*)d_in[6];
  const float* b_hh   = (const float*)d_in[7];
  const float* Wt     = (const float*)d_in[8];
  const float* bt_ih  = (const float*)d_in[9];
  const float* bt_hh  = (const float*)d_in[10];
  const float* wp     = (const float*)d_in[11];
  const float* bp     = (const float*)d_in[12];
  const float* F1     = (const float*)d_in[13];
  const float* b1     = (const float*)d_in[14];
  const float* F2     = (const float*)d_in[15];
  const float* b2     = (const float*)d_in[16];
  const float* ff     = (const float*)d_in[17];
  const float* bff    = (const float*)d_in[18];
  const float* fuse1  = (const float*)d_in[19];
  const float* biasf  = (const float*)d_in[20];
  const float* Wout   = (const float*)d_in[21];
  const float* biasout= (const float*)d_in[22];
  const float* a      = (const float*)d_in[23];
  float* wsf = (float*)d_ws;
  float* outp = (float*)d_out;

  if (ws_size < WS_MIN_BYTES) return;  // cannot run without ~2.2 MB scratch

  kprep<<<dim3(1443), dim3(256), 0, stream>>>(Wih,b_ih,b_hh,Wt,bt_ih,bt_hh,wp,F1,wsf);
  kprep2<<<dim3(1), dim3(64), 0, stream>>>(DisM, wsf);
  dim3 gridAB(128, 32);
  kernA<<<gridAB, NTHR, 0, stream>>>(li,exs,AngleM,bp,b1,F2,b2,wsf);
  kernB<<<gridAB, NTHR, 0, stream>>>(li,bp,ff,bff,fuse1,biasf,Wout,biasout,a,wsf,outp);
  kernC<<<dim3(64), dim3(256), 0, stream>>>(labels, outp);
}

// Round 4
// 5013.557 us; speedup vs baseline: 1.6288x; 1.6288x over previous
//
#include <hip/hip_runtime.h>
#include <hip/hip_bf16.h>

// GCLSTM: B=512, T=32, H=300, K=10. f32 in/out. R3 passed (absmax 9.8e-4, 8166us).
// R4: staged pipeline (PATH2): kern_cells -> con[t][h][b][k] f32 in ws;
//     kern_wp: con1 = relu(wpT x [con_t;con_t-1]) via uniform s_load broadcast
//     (no LDS, no redundancy); kern_attn (sm softmax); kern_final (preds).
// PATH1 (>=100.4MB): R3 kernA + con1 store; kern_final. PATH0: R3 as-is.
// kprobe<bucket> dispatch name reveals ws_size bucket in rocprof.

#define TB 4
#define NTHR 320
#define CH 50

// ws layout (float offsets) — base tables identical to R3
#define OFF_SM    0         // [32][10][512]            163840
#define OFF_WPT   163840    // wpT[h<600][o<300]        180000
#define OFF_WIHP  343840    // ((k*11+i)*3+g)*300+h      99000
#define OFF_BCP   442840    // (k*3+g)*300+h              9000
#define OFF_BTP   451840    // g*300+h                     900
#define OFF_WTP   452740    // (e*3+g)*300+h              3600
#define OFF_WA    456340    // softmax(DisM)                10
#define OFF_SWA   456350    // sum(wA)                       1
#define OFF_F1P   456352    // u32 view: [(h*64+lane)*2+q]  76800 u32
#define BASE_FLOATS 533152
#define OFF_CONF  533152            // con f32 [t][h][b][k] : 49,152,000 floats
#define CON1_BYTE2 ((size_t)(BASE_FLOATS + 49152000) * 4)   // PATH2 con1 (bf16, 98.3MB)
#define CON1_BYTE1 ((size_t)BASE_FLOATS * 4)                // PATH1 con1
#define PATH2_MIN_BYTES (CON1_BYTE2 + (size_t)98304000)     // 297,044,608
#define PATH1_MIN_BYTES (CON1_BYTE1 + (size_t)98304000)     // 100,436,608
#define WS_MIN_BYTES ((size_t)BASE_FLOATS * 4)

__device__ __forceinline__ float sigf(float x){ return 1.0f/(1.0f+__expf(-x)); }
__device__ __forceinline__ float tanhf_(float x){ return 1.0f - 2.0f/(__expf(2.0f*x)+1.0f); }
__device__ __forceinline__ float blo(unsigned u){ return __uint_as_float(u<<16); }
__device__ __forceinline__ float bhi(unsigned u){ return __uint_as_float(u&0xffff0000u); }
__device__ __forceinline__ unsigned short f2us(float f){ return (unsigned short)(__float_as_uint(f)>>16); }

// ---------------- PATH0/1 legacy build (R3, verified) ----------------
__device__ void build_con1(const float* __restrict__ li, const float* __restrict__ wsf,
                           const float* __restrict__ bp, int t, int b0,
                           float (*xs)[11][10], float (*ccs)[CH][12],
                           unsigned short (*con1s)[300][12])
{
  const int tid = threadIdx.x;
  float acc[TB][10];
  #pragma unroll
  for (int b=0;b<TB;b++)
    #pragma unroll
    for (int k=0;k<10;k++) acc[b][k]=0.f;
  const int nchunk = (t==0)?6:12;
  for (int c=0;c<nchunk;c++){
    const int tp = (c<6)? t : (t-1);
    const int h0 = (c<6)? c*CH : (c-6)*CH;
    if (c==0 || c==6){
      for (int p=tid; p<TB*110; p+=NTHR){
        int b=p/110, r=p%110, i=r/10, k=r%10;
        xs[b][i][k] = li[(((b0+b)*32 + tp)*28 + i)*10 + k];
      }
    }
    __syncthreads();
    for (int p=tid; p<10*CH; p+=NTHR){
      int k=p/CH, hr=p%CH, h=h0+hr;
      float ai[TB], ag[TB], ao[TB];
      #pragma unroll
      for (int b=0;b<TB;b++){ ai[b]=0.f; ag[b]=0.f; ao[b]=0.f; }
      const float* W = wsf + OFF_WIHP + k*9900 + h;
      #pragma unroll
      for (int i=0;i<11;i++){
        float wi = W[(i*3+0)*300];
        float wg = W[(i*3+1)*300];
        float wo = W[(i*3+2)*300];
        #pragma unroll
        for (int b=0;b<TB;b++){
          float xv = xs[b][i][k];
          ai[b] += wi*xv; ag[b] += wg*xv; ao[b] += wo*xv;
        }
      }
      float bi = wsf[OFF_BCP + (k*3+0)*300 + h];
      float bg2= wsf[OFF_BCP + (k*3+1)*300 + h];
      float bo = wsf[OFF_BCP + (k*3+2)*300 + h];
      #pragma unroll
      for (int b=0;b<TB;b++){
        float hv = sigf(ao[b]+bo) * tanhf_( sigf(ai[b]+bi) * tanhf_(ag[b]+bg2) );
        if (t==0) con1s[b][h][k] = f2us(hv);
        else      ccs[b][hr][k] = hv;
      }
    }
    __syncthreads();
    if (t>0 && tid<300){
      const int o = tid;
      const float* wrow = wsf + OFF_WPT + (c*CH)*300 + o;
      for (int hr=0;hr<CH;hr++){
        float w = wrow[hr*300];
        #pragma unroll
        for (int b=0;b<TB;b++){
          const float4* r4 = (const float4*)(&ccs[b][hr][0]);
          float4 v0 = r4[0]; float4 v1 = r4[1]; float4 v2 = r4[2];
          acc[b][0] += w*v0.x; acc[b][1] += w*v0.y; acc[b][2] += w*v0.z; acc[b][3] += w*v0.w;
          acc[b][4] += w*v1.x; acc[b][5] += w*v1.y; acc[b][6] += w*v1.z; acc[b][7] += w*v1.w;
          acc[b][8] += w*v2.x; acc[b][9] += w*v2.y;
        }
      }
    }
  }
  if (t>0 && tid<300){
    const int o = tid;
    float bpv = bp[o];
    #pragma unroll
    for (int b=0;b<TB;b++)
      #pragma unroll
      for (int k=0;k<10;k++){
        float v = acc[b][k] + bpv;
        con1s[b][o][k] = f2us(v>0.f? v : 0.f);
      }
  }
  __syncthreads();
}

// device code shared by kernA (attend / wdyn / softmax part)
__device__ void attend_sm(const float* __restrict__ b1, const float* __restrict__ F2,
                          const float* __restrict__ AngleM, const float* __restrict__ b2,
                          const float* __restrict__ wsf, float* __restrict__ smout,
                          int t, int b0,
                          const unsigned short (*con1s)[300][12],
                          const float (*hts)[300], const float (*xse)[2][10])
{
  const int tid = threadIdx.x;
  const int w = tid>>6, lane = tid&63;
  if (w < TB){
    const int b = w, bg = b0+b;
    const unsigned* F1P = (const unsigned*)wsf + OFF_F1P;
    float hb[4];
    #pragma unroll
    for (int jj=0;jj<4;jj++){ int j=jj*64+lane; hb[jj] = (j<200)? b1[j] : 0.f; }
    for (int h=0;h<300;h++){
      float hv = hts[b][h];
      uint2 pp = *(const uint2*)(F1P + ((300+h)*64 + lane)*2);
      hb[0] += blo(pp.x)*hv; hb[1] += bhi(pp.x)*hv;
      hb[2] += blo(pp.y)*hv; hb[3] += bhi(pp.y)*hv;
    }
    float f2v[4];
    #pragma unroll
    for (int jj=0;jj<4;jj++){ int j=jj*64+lane; f2v[jj] = (j<200)? F2[j] : 0.f; }
    float acc[4][10];
    #pragma unroll
    for (int jj=0;jj<4;jj++)
      #pragma unroll
      for (int k=0;k<10;k++) acc[jj][k] = hb[jj];
    for (int h=0;h<300;h++){
      uint2 d0 = *(const uint2*)(&con1s[b][h][0]);
      uint2 d1 = *(const uint2*)(&con1s[b][h][4]);
      unsigned d2 = *(const unsigned*)(&con1s[b][h][8]);
      float cv[10];
      cv[0]=blo(d0.x); cv[1]=bhi(d0.x); cv[2]=blo(d0.y); cv[3]=bhi(d0.y);
      cv[4]=blo(d1.x); cv[5]=bhi(d1.x); cv[6]=blo(d1.y); cv[7]=bhi(d1.y);
      cv[8]=blo(d2);   cv[9]=bhi(d2);
      uint2 pp = *(const uint2*)(F1P + (h*64+lane)*2);
      float a0=blo(pp.x), a1=bhi(pp.x), a2=blo(pp.y), a3=bhi(pp.y);
      #pragma unroll
      for (int k=0;k<10;k++){
        float c = cv[k];
        acc[0][k] += a0*c; acc[1][k] += a1*c; acc[2][k] += a2*c; acc[3][k] += a3*c;
      }
    }
    float f2s8 = F2[200], f2ang = F2[201], b2v = b2[0];
    float wd[10];
    #pragma unroll
    for (int k=0;k<10;k++){
      float part = fmaxf(acc[0][k],0.f)*f2v[0] + fmaxf(acc[1][k],0.f)*f2v[1]
                 + fmaxf(acc[2][k],0.f)*f2v[2] + fmaxf(acc[3][k],0.f)*f2v[3];
      #pragma unroll
      for (int off=32;off>=1;off>>=1) part += __shfl_xor(part,off,64);
      float angv = fabsf(xse[b][1][k] - AngleM[k]) * (1.0f/360.0f);
      float v = part + xse[b][0][k]*f2s8 + angv*f2ang + b2v;
      wd[k] = fmaxf(v,0.f);
    }
    if (lane==0){
      float m = wd[0];
      #pragma unroll
      for (int k=1;k<10;k++) m = fmaxf(m, wd[k]);
      float e[10]; float s=0.f;
      #pragma unroll
      for (int k=0;k<10;k++){ e[k] = __expf(wd[k]-m); s += e[k]; }
      float inv = 1.0f/s;
      float* smp = smout + t*5120 + bg;
      #pragma unroll
      for (int k=0;k<10;k++) smp[k*512] = e[k]*inv;
    }
  }
}

// PATH0/1: legacy kernA (+ optional con1 store for PATH1)
__global__ __launch_bounds__(NTHR,2) void kernA(
    const float* __restrict__ li, const float* __restrict__ exs,
    const float* __restrict__ AngleM, const float* __restrict__ bp,
    const float* __restrict__ b1, const float* __restrict__ F2,
    const float* __restrict__ b2, float* __restrict__ wsf,
    unsigned* __restrict__ con1g)
{
  __shared__ float xs[TB][11][10];
  __shared__ __align__(16) float ccs[TB][CH][12];
  __shared__ __align__(8) unsigned short con1s[TB][300][12];
  __shared__ float hts[TB][300];
  __shared__ float xse[TB][2][10];
  __shared__ float exss[TB][4];
  const int tid = threadIdx.x;
  const int t = blockIdx.y;
  const int b0 = blockIdx.x*TB;

  for (int p=tid;p<TB*20;p+=NTHR){
    int b=p/20, r=p%20, rr=r/10, k=r%10;
    xse[b][rr][k] = li[(((b0+b)*32+t)*28 + (rr?10:8))*10 + k];
  }
  for (int p=tid;p<TB*4;p+=NTHR){
    int b=p/4, e=p%4;
    exss[b][e] = exs[((b0+b)*32+t)*4 + e];
  }
  __syncthreads();
  for (int p=tid;p<TB*300;p+=NTHR){
    int b=p/300, h=p%300;
    float ai=0.f, ag=0.f, ao=0.f;
    #pragma unroll
    for (int e=0;e<4;e++){
      float xv = exss[b][e];
      ai += wsf[OFF_WTP+(e*3+0)*300+h]*xv;
      ag += wsf[OFF_WTP+(e*3+1)*300+h]*xv;
      ao += wsf[OFF_WTP+(e*3+2)*300+h]*xv;
    }
    ai += wsf[OFF_BTP+h]; ag += wsf[OFF_BTP+300+h]; ao += wsf[OFF_BTP+600+h];
    hts[b][h] = sigf(ao)*tanhf_(sigf(ai)*tanhf_(ag));
  }
  build_con1(li, wsf, bp, t, b0, xs, ccs, con1s);
  if (con1g){   // PATH1: persist con1 so kern_final skips the rebuild
    for (int p=tid; p<TB*1500; p+=NTHR){
      int b=p/1500, r=p%1500, h=r/5, kk=r%5;
      con1g[ ((size_t)(t*512 + b0 + b)*300 + h)*5 + kk ] =
        ((const unsigned*)&con1s[b][h][0])[kk];
    }
  }
  attend_sm(b1,F2,AngleM,b2,wsf, wsf+OFF_SM, t,b0, con1s, hts, xse);
}

// PATH0 only: legacy kernB (rebuilds con1)
__global__ __launch_bounds__(NTHR,2) void kernB(
    const float* __restrict__ li, const float* __restrict__ bp,
    const float* __restrict__ ff, const float* __restrict__ bff,
    const float* __restrict__ fuse1, const float* __restrict__ biasf,
    const float* __restrict__ Wout, const float* __restrict__ biasout,
    const float* __restrict__ a, float* __restrict__ wsf,
    float* __restrict__ outp)
{
  __shared__ float xs[TB][11][10];
  __shared__ __align__(16) float ccs[TB][CH][12];
  __shared__ __align__(8) unsigned short con1s[TB][300][12];
  __shared__ float xs17[TB][17][10];
  __shared__ float cats[TB][300];
  __shared__ float wa3s[TB][10];
  __shared__ float dss[TB][17];
  __shared__ float wAs[10];
  const int tid = threadIdx.x;
  const int t = blockIdx.y;
  const int b0 = blockIdx.x*TB;
  for (int p=tid;p<TB*170;p+=NTHR){
    int b=p/170, r=p%170, f=r/10, k=r%10;
    xs17[b][f][k] = li[(((b0+b)*32+t)*28 + 11+f)*10 + k];
  }
  if (tid<10) wAs[tid] = wsf[OFF_WA+tid];
  build_con1(li, wsf, bp, t, b0, xs, ccs, con1s);
  for (int p=tid;p<TB*10;p+=NTHR){
    int b=p/10, k=p%10;
    int g = (b0+b)*10+k;
    wa3s[b][k] = wsf[OFF_SM + t*5120 + (g>>9)*512 + (g&511)];
  }
  for (int p=tid;p<TB*17;p+=NTHR){
    int b=p/17, f=p%17; float s=0.f;
    #pragma unroll
    for (int k=0;k<10;k++) s += xs17[b][f][k]*wAs[k];
    dss[b][f]=s;
  }
  __syncthreads();
  for (int p=tid;p<TB*300;p+=NTHR){
    int b=p/300, h=p%300;
    uint2 d0 = *(const uint2*)(&con1s[b][h][0]);
    uint2 d1 = *(const uint2*)(&con1s[b][h][4]);
    unsigned d2 = *(const unsigned*)(&con1s[b][h][8]);
    float s = blo(d0.x)*wa3s[b][0] + bhi(d0.x)*wa3s[b][1]
            + blo(d0.y)*wa3s[b][2] + bhi(d0.y)*wa3s[b][3]
            + blo(d1.x)*wa3s[b][4] + bhi(d1.x)*wa3s[b][5]
            + blo(d1.y)*wa3s[b][6] + bhi(d1.y)*wa3s[b][7]
            + blo(d2)*wa3s[b][8]   + bhi(d2)*wa3s[b][9];
    cats[b][h]=s;
  }
  __syncthreads();
  const int w = tid>>6, lane = tid&63;
  if (w<TB){
    const int b=w, bg=b0+b;
    const float aa = a[0], swa = wsf[OFF_SWA];
    const int o1 = lane;
    const bool o2v = lane<36;
    const int o2 = o2v ? (64+lane) : 99;
    float fu1 = biasf[o1], fu2 = biasf[o2];
    for (int h=0;h<300;h++){
      float cv = cats[b][h];
      fu1 += cv*fuse1[h*100+o1];
      fu2 += cv*fuse1[h*100+o2];
    }
    float fd1 = bff[o1]*swa, fd2 = bff[o2]*swa;
    #pragma unroll
    for (int f=0;f<17;f++){
      float dv = dss[b][f];
      fd1 += ff[o1*17+f]*dv;
      fd2 += ff[o2*17+f]*dv;
    }
    float v = (aa*fu1+(1.f-aa)*fd1)*Wout[o1];
    if (o2v) v += (aa*fu2+(1.f-aa)*fd2)*Wout[o2];
    #pragma unroll
    for (int off=32;off>=1;off>>=1) v += __shfl_xor(v,off,64);
    if (lane==0) outp[t*512+bg] = v + biasout[0];
  }
}

// ---------------- PATH2 staged kernels ----------------

// cells only, once per (t,b): con f32 -> conf[t][h][b][k]; t==0 also -> con1
__global__ __launch_bounds__(NTHR,2) void kern_cells(
    const float* __restrict__ li, const float* __restrict__ wsf,
    float* __restrict__ conf, unsigned* __restrict__ con1u)
{
  __shared__ float xs[TB][11][10];
  __shared__ float ccs[TB][CH][10];
  const int tid = threadIdx.x;
  const int t = blockIdx.y;
  const int b0 = blockIdx.x*TB;
  for (int p=tid; p<TB*110; p+=NTHR){
    int b=p/110, r=p%110, i=r/10, k=r%10;
    xs[b][i][k] = li[(((b0+b)*32 + t)*28 + i)*10 + k];
  }
  __syncthreads();
  for (int c=0;c<6;c++){
    const int h0 = c*CH;
    for (int p=tid; p<10*CH; p+=NTHR){
      int k=p/CH, hr=p%CH, h=h0+hr;
      float ai[TB], ag[TB], ao[TB];
      #pragma unroll
      for (int b=0;b<TB;b++){ ai[b]=0.f; ag[b]=0.f; ao[b]=0.f; }
      const float* W = wsf + OFF_WIHP + k*9900 + h;
      #pragma unroll
      for (int i=0;i<11;i++){
        float wi = W[(i*3+0)*300];
        float wg = W[(i*3+1)*300];
        float wo = W[(i*3+2)*300];
        #pragma unroll
        for (int b=0;b<TB;b++){
          float xv = xs[b][i][k];
          ai[b] += wi*xv; ag[b] += wg*xv; ao[b] += wo*xv;
        }
      }
      float bi = wsf[OFF_BCP + (k*3+0)*300 + h];
      float bg2= wsf[OFF_BCP + (k*3+1)*300 + h];
      float bo = wsf[OFF_BCP + (k*3+2)*300 + h];
      #pragma unroll
      for (int b=0;b<TB;b++)
        ccs[b][hr][k] = sigf(ao[b]+bo) * tanhf_( sigf(ai[b]+bi) * tanhf_(ag[b]+bg2) );
    }
    __syncthreads();
    for (int p=tid; p<CH*40; p+=NTHR){   // conf[t][h][b][k], 160B rows
      int hr=p/40, q=p%40, b=q/10, k=q%10;
      conf[ (size_t)(t*300+h0+hr)*5120 + (b0+b)*10 + k ] = ccs[b][hr][k];
    }
    if (t==0){   // con1[0] = con0 (bf16)
      for (int p=tid; p<CH*20; p+=NTHR){
        int hr=p/20, q=p%20, b=q/5, kk=q%5;
        float v0 = ccs[b][hr][2*kk], v1 = ccs[b][hr][2*kk+1];
        con1u[ ((size_t)(b0+b)*300 + h0+hr)*5 + kk ] = ((unsigned)f2us(v1)<<16) | f2us(v0);
      }
    }
    __syncthreads();
  }
}

// con1[t>=1] = relu(wpT x [con_t; con_t-1] + bp): thread=o, cc via uniform s_load
__global__ __launch_bounds__(NTHR,2) void kern_wp(
    const float* __restrict__ wpT, const float* __restrict__ bp,
    const float* __restrict__ conf, unsigned* __restrict__ con1u)
{
  const int t  = blockIdx.y + 1;
  const int b0 = blockIdx.x*TB;
  const int o  = threadIdx.x;
  const bool act = o < 300;
  float acc[40];
  #pragma unroll
  for (int j=0;j<40;j++) acc[j]=0.f;
  // half 0: con(t), wpT rows [0,300); half 1: con(t-1), wpT rows [300,600)
  #pragma unroll 1
  for (int half=0; half<2; half++){
    const int tp = half ? (t-1) : t;
    const float* __restrict__ cbase = conf + (size_t)tp*300*5120 + b0*10;
    const float* __restrict__ wbase = wpT + half*300*300;
    #pragma unroll 2
    for (int h=0; h<300; h++){
      const float* cr = cbase + (size_t)h*5120;   // block-uniform address -> s_load
      float w = act ? wbase[h*300+o] : 0.f;
      #pragma unroll
      for (int j=0;j<40;j++) acc[j] = fmaf(w, cr[j], acc[j]);
    }
  }
  if (act){
    float bpv = bp[o];
    #pragma unroll
    for (int b=0;b<TB;b++)
      #pragma unroll
      for (int kk=0;kk<5;kk++){
        float v0 = acc[b*10+2*kk]   + bpv; v0 = v0>0.f? v0 : 0.f;
        float v1 = acc[b*10+2*kk+1] + bpv; v1 = v1>0.f? v1 : 0.f;
        con1u[ ((size_t)(t*512 + b0+b)*300 + o)*5 + kk ] = ((unsigned)f2us(v1)<<16) | f2us(v0);
      }
  }
}

// attend: load con1 tile from ws, compute hts, wdyn, softmax -> sm
__global__ __launch_bounds__(NTHR,2) void kern_attn(
    const float* __restrict__ li, const float* __restrict__ exs,
    const float* __restrict__ AngleM, const float* __restrict__ b1,
    const float* __restrict__ F2, const float* __restrict__ b2,
    float* __restrict__ wsf, const unsigned* __restrict__ con1u)
{
  __shared__ __align__(8) unsigned short con1s[TB][300][12];
  __shared__ float hts[TB][300];
  __shared__ float xse[TB][2][10];
  __shared__ float exss[TB][4];
  const int tid = threadIdx.x;
  const int t = blockIdx.y;
  const int b0 = blockIdx.x*TB;
  for (int p=tid;p<TB*20;p+=NTHR){
    int b=p/20, r=p%20, rr=r/10, k=r%10;
    xse[b][rr][k] = li[(((b0+b)*32+t)*28 + (rr?10:8))*10 + k];
  }
  for (int p=tid;p<TB*4;p+=NTHR){
    int b=p/4, e=p%4;
    exss[b][e] = exs[((b0+b)*32+t)*4 + e];
  }
  for (int p=tid;p<TB*1500;p+=NTHR){
    int b=p/1500, r=p%1500, h=r/5, kk=r%5;
    ((unsigned*)&con1s[b][h][0])[kk] = con1u[ ((size_t)(t*512+b0+b)*300+h)*5 + kk ];
  }
  __syncthreads();
  for (int p=tid;p<TB*300;p+=NTHR){
    int b=p/300, h=p%300;
    float ai=0.f, ag=0.f, ao=0.f;
    #pragma unroll
    for (int e=0;e<4;e++){
      float xv = exss[b][e];
      ai += wsf[OFF_WTP+(e*3+0)*300+h]*xv;
      ag += wsf[OFF_WTP+(e*3+1)*300+h]*xv;
      ao += wsf[OFF_WTP+(e*3+2)*300+h]*xv;
    }
    ai += wsf[OFF_BTP+h]; ag += wsf[OFF_BTP+300+h]; ao += wsf[OFF_BTP+600+h];
    hts[b][h] = sigf(ao)*tanhf_(sigf(ai)*tanhf_(ag));
  }
  __syncthreads();
  attend_sm(b1,F2,AngleM,b2,wsf, wsf+OFF_SM, t,b0, con1s, hts, xse);
}

// final: load con1 tile, gather scrambled softmax, fuse, write preds
template<int WSB>
__global__ __launch_bounds__(NTHR,2) void kern_final(
    const float* __restrict__ li, const float* __restrict__ ff,
    const float* __restrict__ bff, const float* __restrict__ fuse1,
    const float* __restrict__ biasf, const float* __restrict__ Wout,
    const float* __restrict__ biasout, const float* __restrict__ a,
    float* __restrict__ wsf, const unsigned* __restrict__ con1u,
    float* __restrict__ outp)
{
  __shared__ __align__(8) unsigned short con1s[TB][300][12];
  __shared__ float xs17[TB][17][10];
  __shared__ float cats[TB][300];
  __shared__ float wa3s[TB][10];
  __shared__ float dss[TB][17];
  __shared__ float wAs[10];
  const int tid = threadIdx.x;
  const int t = blockIdx.y;
  const int b0 = blockIdx.x*TB;
  for (int p=tid;p<TB*170;p+=NTHR){
    int b=p/170, r=p%170, f=r/10, k=r%10;
    xs17[b][f][k] = li[(((b0+b)*32+t)*28 + 11+f)*10 + k];
  }
  if (tid<10) wAs[tid] = wsf[OFF_WA+tid];
  for (int p=tid;p<TB*1500;p+=NTHR){
    int b=p/1500, r=p%1500, h=r/5, kk=r%5;
    ((unsigned*)&con1s[b][h][0])[kk] = con1u[ ((size_t)(t*512+b0+b)*300+h)*5 + kk ];
  }
  __syncthreads();
  for (int p=tid;p<TB*10;p+=NTHR){
    int b=p/10, k=p%10;
    int g = (b0+b)*10+k;
    wa3s[b][k] = wsf[OFF_SM + t*5120 + (g>>9)*512 + (g&511)];
  }
  for (int p=tid;p<TB*17;p+=NTHR){
    int b=p/17, f=p%17; float s=0.f;
    #pragma unroll
    for (int k=0;k<10;k++) s += xs17[b][f][k]*wAs[k];
    dss[b][f]=s;
  }
  __syncthreads();
  for (int p=tid;p<TB*300;p+=NTHR){
    int b=p/300, h=p%300;
    uint2 d0 = *(const uint2*)(&con1s[b][h][0]);
    uint2 d1 = *(const uint2*)(&con1s[b][h][4]);
    unsigned d2 = *(const unsigned*)(&con1s[b][h][8]);
    float s = blo(d0.x)*wa3s[b][0] + bhi(d0.x)*wa3s[b][1]
            + blo(d0.y)*wa3s[b][2] + bhi(d0.y)*wa3s[b][3]
            + blo(d1.x)*wa3s[b][4] + bhi(d1.x)*wa3s[b][5]
            + blo(d1.y)*wa3s[b][6] + bhi(d1.y)*wa3s[b][7]
            + blo(d2)*wa3s[b][8]   + bhi(d2)*wa3s[b][9];
    cats[b][h]=s;
  }
  __syncthreads();
  const int w = tid>>6, lane = tid&63;
  if (w<TB){
    const int b=w, bg=b0+b;
    const float aa = a[0], swa = wsf[OFF_SWA];
    const int o1 = lane;
    const bool o2v = lane<36;
    const int o2 = o2v ? (64+lane) : 99;
    float fu1 = biasf[o1], fu2 = biasf[o2];
    for (int h=0;h<300;h++){
      float cv = cats[b][h];
      fu1 += cv*fuse1[h*100+o1];
      fu2 += cv*fuse1[h*100+o2];
    }
    float fd1 = bff[o1]*swa, fd2 = bff[o2]*swa;
    #pragma unroll
    for (int f=0;f<17;f++){
      float dv = dss[b][f];
      fd1 += ff[o1*17+f]*dv;
      fd2 += ff[o2*17+f]*dv;
    }
    float v = (aa*fu1+(1.f-aa)*fd1)*Wout[o1];
    if (o2v) v += (aa*fu2+(1.f-aa)*fd2)*Wout[o2];
    #pragma unroll
    for (int off=32;off>=1;off>>=1) v += __shfl_xor(v,off,64);
    if (lane==0) outp[t*512+bg] = v + biasout[0];
  }
}

__global__ void kernC(const float* __restrict__ labels, float* __restrict__ outp){
  int p = blockIdx.x*256 + threadIdx.x;
  if (p < 16384){
    int t=p>>9, b=p&511;
    outp[16384+p] = labels[b*32+t];
  }
}

template<int BUCKET>
__global__ void kprobe(float* wsf){
  if (wsf == (float*)1) wsf[0] = (float)BUCKET;  // never true; dispatch name = ws probe
}

__global__ void kprep(const float* __restrict__ Wih, const float* __restrict__ b_ih,
                      const float* __restrict__ b_hh, const float* __restrict__ Wt,
                      const float* __restrict__ bt_ih, const float* __restrict__ bt_hh,
                      const float* __restrict__ wp, const float* __restrict__ F1,
                      float* __restrict__ wsf)
{
  int n = blockIdx.x*256 + threadIdx.x;
  if (n < 180000){ int h=n/300, o=n%300; wsf[OFF_WPT+n] = wp[o*600+h]; return; }
  n -= 180000;
  if (n < 99000){
    int h=n%300; int q=n/300; int g=q%3; int m=q/3; int i=m%11; int k=m/11;
    int G = h + (g==0?0:(g==1?600:900));
    wsf[OFF_WIHP+n] = Wih[(k*1200 + G)*11 + i]; return;
  }
  n -= 99000;
  if (n < 9000){
    int h=n%300; int q=n/300; int g=q%3, k=q/3;
    int G = h + (g==0?0:(g==1?600:900));
    wsf[OFF_BCP+n] = b_ih[k*1200+G] + b_hh[k*1200+G]; return;
  }
  n -= 9000;
  if (n < 900){
    int h=n%300, g=n/300;
    int G = h + (g==0?0:(g==1?600:900));
    wsf[OFF_BTP+n] = bt_ih[G]+bt_hh[G]; return;
  }
  n -= 900;
  if (n < 3600){
    int h=n%300; int q=n/300; int g=q%3, e=q/3;
    int G = h + (g==0?0:(g==1?600:900));
    wsf[OFF_WTP+n] = Wt[G*4+e]; return;
  }
  n -= 3600;
  if (n < 76800){
    int q=n%2; int r=n/2; int lane=r%64; int h=r/64;
    int j0 = q*128 + lane, j1 = q*128 + 64 + lane;
    float v0 = (j0<200)? F1[h*200+j0] : 0.f;
    float v1 = (j1<200)? F1[h*200+j1] : 0.f;
    unsigned u = (__float_as_uint(v1)&0xffff0000u) | (__float_as_uint(v0)>>16);
    ((unsigned*)wsf)[OFF_F1P + n] = u; return;
  }
}

__global__ void kprep2(const float* __restrict__ DisM, float* __restrict__ wsf){
  if (threadIdx.x==0 && blockIdx.x==0){
    float m = DisM[0];
    for (int k=1;k<10;k++) m = fmaxf(m, DisM[k]);
    float e[10]; float s=0.f;
    for (int k=0;k<10;k++){ e[k]=__expf(DisM[k]-m); s+=e[k]; }
    float inv=1.0f/s; float sw=0.f;
    for (int k=0;k<10;k++){ float v=e[k]*inv; wsf[OFF_WA+k]=v; sw+=v; }
    wsf[OFF_SWA]=sw;
  }
}

extern "C" void kernel_launch(void* const* d_in, const int* in_sizes, int n_in,
                              void* d_out, int out_size, void* d_ws, size_t ws_size,
                              hipStream_t stream)
{
  const float* li     = (const float*)d_in[0];
  const float* labels = (const float*)d_in[1];
  const float* exs    = (const float*)d_in[2];
  const float* DisM   = (const float*)d_in[3];
  const float* AngleM = (const float*)d_in[4];
  const float* Wih    = (const float*)d_in[5];
  const float* b_ih   = (const float*)d_in[6];
  const float* b_hh   = (const float*)d_in[7];
  const float* Wt     = (const float*)d_in[8];
  const float* bt_ih  = (const float*)d_in[9];
  const float* bt_hh  = (const float*)d_in[10];
  const float* wp     = (const float*)d_in[11];
  const float* bp     = (const float*)d_in[12];
  const float* F1     = (const float*)d_in[13];
  const float* b1     = (const float*)d_in[14];
  const float* F2     = (const float*)d_in[15];
  const float* b2     = (const float*)d_in[16];
  const float* ff     = (const float*)d_in[17];
  const float* bff    = (const float*)d_in[18];
  const float* fuse1  = (const float*)d_in[19];
  const float* biasf  = (const float*)d_in[20];
  const float* Wout   = (const float*)d_in[21];
  const float* biasout= (const float*)d_in[22];
  const float* a      = (const float*)d_in[23];
  float* wsf = (float*)d_ws;
  float* outp = (float*)d_out;

  if (ws_size < WS_MIN_BYTES) return;

  kprep<<<dim3(1443), dim3(256), 0, stream>>>(Wih,b_ih,b_hh,Wt,bt_ih,bt_hh,wp,F1,wsf);
  kprep2<<<dim3(1), dim3(64), 0, stream>>>(DisM, wsf);

  // ws-size probe: bucket visible as kprobe<N> in rocprof dispatch names
  size_t MB = (size_t)1<<20;
  if      (ws_size <   4*MB)          kprobe<0><<<1,64,0,stream>>>(wsf);
  else if (ws_size <  16*MB)          kprobe<1><<<1,64,0,stream>>>(wsf);
  else if (ws_size <  64*MB)          kprobe<2><<<1,64,0,stream>>>(wsf);
  else if (ws_size < PATH1_MIN_BYTES) kprobe<3><<<1,64,0,stream>>>(wsf);
  else if (ws_size < 160*MB)          kprobe<4><<<1,64,0,stream>>>(wsf);
  else if (ws_size < PATH2_MIN_BYTES) kprobe<5><<<1,64,0,stream>>>(wsf);
  else if (ws_size < 512*MB)          kprobe<6><<<1,64,0,stream>>>(wsf);
  else                                kprobe<7><<<1,64,0,stream>>>(wsf);

  dim3 gridAB(128, 32);
  if (ws_size >= PATH2_MIN_BYTES){
    float*    conf  = wsf + OFF_CONF;
    unsigned* con1u = (unsigned*)((char*)d_ws + CON1_BYTE2);
    kern_cells<<<gridAB, NTHR, 0, stream>>>(li, wsf, conf, con1u);
    kern_wp   <<<dim3(128,31), NTHR, 0, stream>>>(wsf+OFF_WPT, bp, conf, con1u);
    kern_attn <<<gridAB, NTHR, 0, stream>>>(li, exs, AngleM, b1, F2, b2, wsf, con1u);
    kern_final<2><<<gridAB, NTHR, 0, stream>>>(li, ff, bff, fuse1, biasf, Wout, biasout, a,
                                               wsf, con1u, outp);
  } else if (ws_size >= PATH1_MIN_BYTES){
    unsigned* con1u = (unsigned*)((char*)d_ws + CON1_BYTE1);
    kernA<<<gridAB, NTHR, 0, stream>>>(li,exs,AngleM,bp,b1,F2,b2,wsf, con1u);
    kern_final<1><<<gridAB, NTHR, 0, stream>>>(li, ff, bff, fuse1, biasf, Wout, biasout, a,
                                               wsf, con1u, outp);
  } else {
    kernA<<<gridAB, NTHR, 0, stream>>>(li,exs,AngleM,bp,b1,F2,b2,wsf, (unsigned*)nullptr);
    kernB<<<gridAB, NTHR, 0, stream>>>(li,bp,ff,bff,fuse1,biasf,Wout,biasout,a,wsf,outp);
  }
  kernC<<<dim3(64), dim3(256), 0, stream>>>(labels, outp);
}

// Round 5
// 1406.761 us; speedup vs baseline: 5.8051x; 3.5639x over previous
//
#include <hip/hip_runtime.h>
#include <hip/hip_bf16.h>

// GCLSTM: B=512, T=32, H=300, K=10. f32 in/out.
// R5: wp projection as bf16 MFMA GEMM (con1[300,5120] = W[300x600] @ CC[600,5120]
// per t), with cells RECOMPUTED per block into LDS (no conf buffer).
// Memory: base 1.81MB + con1u 98.3MB = 100.1MB (< proven-available 100.44MB).
// Pipeline: kprep -> kern_con0 (t=0) -> kern_wpmfma (t=1..31) -> kern_attn -> kern_final.

#define TB 4
#define NTHR 320
#define KP 616            // padded K stride (bf16 elems): 600 real + 8 zero + 8 pad

// ws layout (float/u32-slot offsets)
#define OFF_SM    0         // softmax scratch [32][10][512]      163840
#define OFF_WBF   163840    // W bf16 [o 320][k 616] (u32 view)    98560
#define OFF_WIHP  262400    // ((k*11+i)*3+g)*300+h                99000
#define OFF_BCP   361400    // (k*3+g)*300+h                        9000
#define OFF_BTP   370400    // g*300+h                               900
#define OFF_WTP   371300    // (e*3+g)*300+h                        3600
#define OFF_WA    374900    // softmax(DisM)                          10
#define OFF_SWA   374910    // sum(wA)                                 1
#define OFF_F1P   374912    // F1 bf16x2 packed (u32 view)         76800
#define BASE_FLOATS 451712
#define CON1_BYTE ((size_t)BASE_FLOATS * 4)                 // 1,806,848
#define WS_MIN_BYTES (CON1_BYTE + (size_t)98304000)         // 100,110,848

typedef __attribute__((ext_vector_type(8))) short s16x8;
typedef __attribute__((ext_vector_type(4))) float f32x4;

__device__ __forceinline__ float sigf(float x){ return 1.0f/(1.0f+__expf(-x)); }
__device__ __forceinline__ float tanhf_(float x){ return 1.0f - 2.0f/(__expf(2.0f*x)+1.0f); }
__device__ __forceinline__ float blo(unsigned u){ return __uint_as_float(u<<16); }
__device__ __forceinline__ float bhi(unsigned u){ return __uint_as_float(u&0xffff0000u); }
__device__ __forceinline__ unsigned short f2us(float f){ return (unsigned short)(__float_as_uint(f)>>16); }
__device__ __forceinline__ unsigned short f2usr(float f){   // RNE bf16
  __hip_bfloat16 h = __float2bfloat16(f);
  return *(unsigned short*)&h;
}

// ---------------- t = 0: con1 = con0 (cells only) ----------------
__global__ __launch_bounds__(NTHR,2) void kern_con0(
    const float* __restrict__ li, const float* __restrict__ wsf,
    unsigned* __restrict__ con1u)
{
  __shared__ float xs[TB][11][10];
  __shared__ unsigned short c0[TB][300][10];   // 24,000 B
  const int tid = threadIdx.x;
  const int b0 = blockIdx.x*TB;
  for (int p=tid; p<TB*110; p+=NTHR){
    int b=p/110, r=p%110, i=r/10, k=r%10;
    xs[b][i][k] = li[(((b0+b)*32 + 0)*28 + i)*10 + k];
  }
  __syncthreads();
  for (int p=tid; p<3000; p+=NTHR){
    int k=p/300, h=p%300;
    float ai[TB], ag[TB], ao[TB];
    #pragma unroll
    for (int b=0;b<TB;b++){ ai[b]=0.f; ag[b]=0.f; ao[b]=0.f; }
    const float* W = wsf + OFF_WIHP + k*9900 + h;
    #pragma unroll
    for (int i=0;i<11;i++){
      float wi = W[(i*3+0)*300];
      float wg = W[(i*3+1)*300];
      float wo = W[(i*3+2)*300];
      #pragma unroll
      for (int b=0;b<TB;b++){
        float xv = xs[b][i][k];
        ai[b] += wi*xv; ag[b] += wg*xv; ao[b] += wo*xv;
      }
    }
    float bi = wsf[OFF_BCP + (k*3+0)*300 + h];
    float bg2= wsf[OFF_BCP + (k*3+1)*300 + h];
    float bo = wsf[OFF_BCP + (k*3+2)*300 + h];
    #pragma unroll
    for (int b=0;b<TB;b++){
      float hv = sigf(ao[b]+bo) * tanhf_( sigf(ai[b]+bi) * tanhf_(ag[b]+bg2) );
      c0[b][h][k] = f2us(hv);
    }
  }
  __syncthreads();
  for (int p=tid; p<TB*300; p+=NTHR){
    int b=p/300, o=p%300;
    const unsigned short* src = &c0[b][o][0];   // 20B offset -> 4B aligned
    unsigned* dst = con1u + ((size_t)(b0+b)*300 + o)*5;
    #pragma unroll
    for (int kk=0;kk<5;kk++)
      dst[kk] = *(const unsigned*)(src + 2*kk);
  }
}

// ---------------- t = 1..31: fused cells + MFMA wp GEMM ----------------
__global__ __launch_bounds__(NTHR,2) void kern_wpmfma(
    const float* __restrict__ li, const float* __restrict__ wsf,
    const float* __restrict__ bp, unsigned* __restrict__ con1u)
{
  __shared__ __align__(16) unsigned short cct[48][KP];  // 59,136 B
  __shared__ float xs[2][TB][11][10];                   //  3,520 B
  const int tid = threadIdx.x;
  const int t  = blockIdx.y + 1;     // 1..31
  const int b0 = blockIdx.x*TB;

  // stage x(t) and x(t-1)
  for (int p=tid; p<2*TB*110; p+=NTHR){
    int half=p/440, r=p%440, b=r/110, q=r%110, i=q/10, k=q%10;
    int tp = half ? (t-1) : t;
    xs[half][b][i][k] = li[(((b0+b)*32 + tp)*28 + i)*10 + k];
  }
  // zero k-pad cols [600,616) of rows 0..39, and rows 40..47 entirely
  {
    unsigned* cw = (unsigned*)&cct[0][0];
    for (int p=tid; p<40*8; p+=NTHR){            // rows 0..39, cols 600..615 (8 u32)
      int n=p/8, c=p%8;
      cw[(n*KP + 600)/2 + c] = 0u;
    }
    for (int p=tid; p<8*(KP/2); p+=NTHR){        // rows 40..47 full
      int n=40+p/(KP/2), c=p%(KP/2);
      cw[(n*KP)/2 + c] = 0u;
    }
  }
  __syncthreads();

  // cells for both timesteps -> cct[n=b*10+k][h + 300*half] (bf16 RNE)
  for (int p=tid; p<6000; p+=NTHR){
    int half=p/3000, q=p%3000, k=q/300, h=q%300;
    float ai[TB], ag[TB], ao[TB];
    #pragma unroll
    for (int b=0;b<TB;b++){ ai[b]=0.f; ag[b]=0.f; ao[b]=0.f; }
    const float* W = wsf + OFF_WIHP + k*9900 + h;
    #pragma unroll
    for (int i=0;i<11;i++){
      float wi = W[(i*3+0)*300];
      float wg = W[(i*3+1)*300];
      float wo = W[(i*3+2)*300];
      #pragma unroll
      for (int b=0;b<TB;b++){
        float xv = xs[half][b][i][k];
        ai[b] += wi*xv; ag[b] += wg*xv; ao[b] += wo*xv;
      }
    }
    float bi = wsf[OFF_BCP + (k*3+0)*300 + h];
    float bg2= wsf[OFF_BCP + (k*3+1)*300 + h];
    float bo = wsf[OFF_BCP + (k*3+2)*300 + h];
    #pragma unroll
    for (int b=0;b<TB;b++){
      float hv = sigf(ao[b]+bo) * tanhf_( sigf(ai[b]+bi) * tanhf_(ag[b]+bg2) );
      cct[b*10+k][h + 300*half] = f2usr(hv);
    }
  }
  __syncthreads();

  // MFMA GEMM: D[o 304][n 48] = W[304x608] * CC[608x48]
  // wave w: Mtiles w*4..w*4+3 (tile 19 = zero rows, discarded); Ntiles 0..2.
  const int w = tid>>6, lane = tid&63;
  const int lo = lane&15, qd = lane>>4;
  const unsigned short* wbf = (const unsigned short*)((const unsigned*)wsf + OFF_WBF);
  f32x4 acc[4][3];
  #pragma unroll
  for (int i=0;i<4;i++)
    #pragma unroll
    for (int nt=0;nt<3;nt++) acc[i][nt] = (f32x4){0.f,0.f,0.f,0.f};

  for (int ks=0; ks<19; ks++){
    const int kb = ks*32 + qd*8;
    s16x8 Bv[3], Av[4];
    #pragma unroll
    for (int nt=0;nt<3;nt++)
      Bv[nt] = *(const s16x8*)&cct[nt*16 + lo][kb];
    #pragma unroll
    for (int i=0;i<4;i++){
      int o = (w*4+i)*16 + lo;
      Av[i] = *(const s16x8*)(wbf + (size_t)o*KP + kb);
    }
    #pragma unroll
    for (int i=0;i<4;i++)
      #pragma unroll
      for (int nt=0;nt<3;nt++)
        acc[i][nt] = __builtin_amdgcn_mfma_f32_16x16x32_bf16(Av[i], Bv[nt], acc[i][nt], 0,0,0);
  }
  __syncthreads();   // done reading cct; reuse as output staging

  // epilogue: +bp, relu, bf16 -> out[o][n] (stride 48), then coalesced store
  unsigned short* out = &cct[0][0];
  #pragma unroll
  for (int i=0;i<4;i++){
    int mt = w*4+i;
    if (mt < 19){
      #pragma unroll
      for (int nt=0;nt<3;nt++){
        int n = nt*16 + lo;
        #pragma unroll
        for (int r=0;r<4;r++){
          int o = mt*16 + qd*4 + r;
          if (o < 300 && n < 40){
            float v = acc[i][nt][r] + bp[o];
            out[o*48 + n] = f2us(v>0.f ? v : 0.f);
          }
        }
      }
    }
  }
  __syncthreads();
  for (int p=tid; p<TB*300; p+=NTHR){
    int b=p/300, o=p%300;
    const unsigned short* src = out + o*48 + b*10;    // 4B aligned
    unsigned* dst = con1u + ((size_t)(t*512 + b0+b)*300 + o)*5;
    #pragma unroll
    for (int kk=0;kk<5;kk++)
      dst[kk] = *(const unsigned*)(src + 2*kk);
  }
}

// ---------------- attend / softmax (verified via R3 kernA path) ----------------
__device__ void attend_sm(const float* __restrict__ b1, const float* __restrict__ F2,
                          const float* __restrict__ AngleM, const float* __restrict__ b2,
                          const float* __restrict__ wsf, float* __restrict__ smout,
                          int t, int b0,
                          const unsigned short (*con1s)[300][12],
                          const float (*hts)[300], const float (*xse)[2][10])
{
  const int tid = threadIdx.x;
  const int w = tid>>6, lane = tid&63;
  if (w < TB){
    const int b = w, bg = b0+b;
    const unsigned* F1P = (const unsigned*)wsf + OFF_F1P;
    float hb[4];
    #pragma unroll
    for (int jj=0;jj<4;jj++){ int j=jj*64+lane; hb[jj] = (j<200)? b1[j] : 0.f; }
    for (int h=0;h<300;h++){
      float hv = hts[b][h];
      uint2 pp = *(const uint2*)(F1P + ((300+h)*64 + lane)*2);
      hb[0] += blo(pp.x)*hv; hb[1] += bhi(pp.x)*hv;
      hb[2] += blo(pp.y)*hv; hb[3] += bhi(pp.y)*hv;
    }
    float f2v[4];
    #pragma unroll
    for (int jj=0;jj<4;jj++){ int j=jj*64+lane; f2v[jj] = (j<200)? F2[j] : 0.f; }
    float acc[4][10];
    #pragma unroll
    for (int jj=0;jj<4;jj++)
      #pragma unroll
      for (int k=0;k<10;k++) acc[jj][k] = hb[jj];
    for (int h=0;h<300;h++){
      uint2 d0 = *(const uint2*)(&con1s[b][h][0]);
      uint2 d1 = *(const uint2*)(&con1s[b][h][4]);
      unsigned d2 = *(const unsigned*)(&con1s[b][h][8]);
      float cv[10];
      cv[0]=blo(d0.x); cv[1]=bhi(d0.x); cv[2]=blo(d0.y); cv[3]=bhi(d0.y);
      cv[4]=blo(d1.x); cv[5]=bhi(d1.x); cv[6]=blo(d1.y); cv[7]=bhi(d1.y);
      cv[8]=blo(d2);   cv[9]=bhi(d2);
      uint2 pp = *(const uint2*)(F1P + (h*64+lane)*2);
      float a0=blo(pp.x), a1=bhi(pp.x), a2=blo(pp.y), a3=bhi(pp.y);
      #pragma unroll
      for (int k=0;k<10;k++){
        float c = cv[k];
        acc[0][k] += a0*c; acc[1][k] += a1*c; acc[2][k] += a2*c; acc[3][k] += a3*c;
      }
    }
    float f2s8 = F2[200], f2ang = F2[201], b2v = b2[0];
    float wd[10];
    #pragma unroll
    for (int k=0;k<10;k++){
      float part = fmaxf(acc[0][k],0.f)*f2v[0] + fmaxf(acc[1][k],0.f)*f2v[1]
                 + fmaxf(acc[2][k],0.f)*f2v[2] + fmaxf(acc[3][k],0.f)*f2v[3];
      #pragma unroll
      for (int off=32;off>=1;off>>=1) part += __shfl_xor(part,off,64);
      float angv = fabsf(xse[b][1][k] - AngleM[k]) * (1.0f/360.0f);
      float v = part + xse[b][0][k]*f2s8 + angv*f2ang + b2v;
      wd[k] = fmaxf(v,0.f);
    }
    if (lane==0){
      float m = wd[0];
      #pragma unroll
      for (int k=1;k<10;k++) m = fmaxf(m, wd[k]);
      float e[10]; float s=0.f;
      #pragma unroll
      for (int k=0;k<10;k++){ e[k] = __expf(wd[k]-m); s += e[k]; }
      float inv = 1.0f/s;
      float* smp = smout + t*5120 + bg;
      #pragma unroll
      for (int k=0;k<10;k++) smp[k*512] = e[k]*inv;
    }
  }
}

__global__ __launch_bounds__(NTHR,2) void kern_attn(
    const float* __restrict__ li, const float* __restrict__ exs,
    const float* __restrict__ AngleM, const float* __restrict__ b1,
    const float* __restrict__ F2, const float* __restrict__ b2,
    float* __restrict__ wsf, const unsigned* __restrict__ con1u)
{
  __shared__ __align__(8) unsigned short con1s[TB][300][12];
  __shared__ float hts[TB][300];
  __shared__ float xse[TB][2][10];
  __shared__ float exss[TB][4];
  const int tid = threadIdx.x;
  const int t = blockIdx.y;
  const int b0 = blockIdx.x*TB;
  for (int p=tid;p<TB*20;p+=NTHR){
    int b=p/20, r=p%20, rr=r/10, k=r%10;
    xse[b][rr][k] = li[(((b0+b)*32+t)*28 + (rr?10:8))*10 + k];
  }
  for (int p=tid;p<TB*4;p+=NTHR){
    int b=p/4, e=p%4;
    exss[b][e] = exs[((b0+b)*32+t)*4 + e];
  }
  for (int p=tid;p<TB*1500;p+=NTHR){
    int b=p/1500, r=p%1500, h=r/5, kk=r%5;
    ((unsigned*)&con1s[b][h][0])[kk] = con1u[ ((size_t)(t*512+b0+b)*300+h)*5 + kk ];
  }
  __syncthreads();
  for (int p=tid;p<TB*300;p+=NTHR){
    int b=p/300, h=p%300;
    float ai=0.f, ag=0.f, ao=0.f;
    #pragma unroll
    for (int e=0;e<4;e++){
      float xv = exss[b][e];
      ai += wsf[OFF_WTP+(e*3+0)*300+h]*xv;
      ag += wsf[OFF_WTP+(e*3+1)*300+h]*xv;
      ao += wsf[OFF_WTP+(e*3+2)*300+h]*xv;
    }
    ai += wsf[OFF_BTP+h]; ag += wsf[OFF_BTP+300+h]; ao += wsf[OFF_BTP+600+h];
    hts[b][h] = sigf(ao)*tanhf_(sigf(ai)*tanhf_(ag));
  }
  __syncthreads();
  attend_sm(b1,F2,AngleM,b2,wsf, wsf+OFF_SM, t,b0, con1s, hts, xse);
}

__global__ __launch_bounds__(NTHR,2) void kern_final(
    const float* __restrict__ li, const float* __restrict__ ff,
    const float* __restrict__ bff, const float* __restrict__ fuse1,
    const float* __restrict__ biasf, const float* __restrict__ Wout,
    const float* __restrict__ biasout, const float* __restrict__ a,
    float* __restrict__ wsf, const unsigned* __restrict__ con1u,
    float* __restrict__ outp)
{
  __shared__ __align__(8) unsigned short con1s[TB][300][12];
  __shared__ float xs17[TB][17][10];
  __shared__ float cats[TB][300];
  __shared__ float wa3s[TB][10];
  __shared__ float dss[TB][17];
  __shared__ float wAs[10];
  const int tid = threadIdx.x;
  const int t = blockIdx.y;
  const int b0 = blockIdx.x*TB;
  for (int p=tid;p<TB*170;p+=NTHR){
    int b=p/170, r=p%170, f=r/10, k=r%10;
    xs17[b][f][k] = li[(((b0+b)*32+t)*28 + 11+f)*10 + k];
  }
  if (tid<10) wAs[tid] = wsf[OFF_WA+tid];
  for (int p=tid;p<TB*1500;p+=NTHR){
    int b=p/1500, r=p%1500, h=r/5, kk=r%5;
    ((unsigned*)&con1s[b][h][0])[kk] = con1u[ ((size_t)(t*512+b0+b)*300+h)*5 + kk ];
  }
  __syncthreads();
  for (int p=tid;p<TB*10;p+=NTHR){
    int b=p/10, k=p%10;
    int g = (b0+b)*10+k;
    wa3s[b][k] = wsf[OFF_SM + t*5120 + (g>>9)*512 + (g&511)];
  }
  for (int p=tid;p<TB*17;p+=NTHR){
    int b=p/17, f=p%17; float s=0.f;
    #pragma unroll
    for (int k=0;k<10;k++) s += xs17[b][f][k]*wAs[k];
    dss[b][f]=s;
  }
  __syncthreads();
  for (int p=tid;p<TB*300;p+=NTHR){
    int b=p/300, h=p%300;
    uint2 d0 = *(const uint2*)(&con1s[b][h][0]);
    uint2 d1 = *(const uint2*)(&con1s[b][h][4]);
    unsigned d2 = *(const unsigned*)(&con1s[b][h][8]);
    float s = blo(d0.x)*wa3s[b][0] + bhi(d0.x)*wa3s[b][1]
            + blo(d0.y)*wa3s[b][2] + bhi(d0.y)*wa3s[b][3]
            + blo(d1.x)*wa3s[b][4] + bhi(d1.x)*wa3s[b][5]
            + blo(d1.y)*wa3s[b][6] + bhi(d1.y)*wa3s[b][7]
            + blo(d2)*wa3s[b][8]   + bhi(d2)*wa3s[b][9];
    cats[b][h]=s;
  }
  __syncthreads();
  const int w = tid>>6, lane = tid&63;
  if (w<TB){
    const int b=w, bg=b0+b;
    const float aa = a[0], swa = wsf[OFF_SWA];
    const int o1 = lane;
    const bool o2v = lane<36;
    const int o2 = o2v ? (64+lane) : 99;
    float fu1 = biasf[o1], fu2 = biasf[o2];
    for (int h=0;h<300;h++){
      float cv = cats[b][h];
      fu1 += cv*fuse1[h*100+o1];
      fu2 += cv*fuse1[h*100+o2];
    }
    float fd1 = bff[o1]*swa, fd2 = bff[o2]*swa;
    #pragma unroll
    for (int f=0;f<17;f++){
      float dv = dss[b][f];
      fd1 += ff[o1*17+f]*dv;
      fd2 += ff[o2*17+f]*dv;
    }
    float v = (aa*fu1+(1.f-aa)*fd1)*Wout[o1];
    if (o2v) v += (aa*fu2+(1.f-aa)*fd2)*Wout[o2];
    #pragma unroll
    for (int off=32;off>=1;off>>=1) v += __shfl_xor(v,off,64);
    if (lane==0) outp[t*512+bg] = v + biasout[0];
  }
}

__global__ void kernC(const float* __restrict__ labels, float* __restrict__ outp){
  int p = blockIdx.x*256 + threadIdx.x;
  if (p < 16384){
    int t=p>>9, b=p&511;
    outp[16384+p] = labels[b*32+t];
  }
}

__global__ void kprep(const float* __restrict__ Wih, const float* __restrict__ b_ih,
                      const float* __restrict__ b_hh, const float* __restrict__ Wt,
                      const float* __restrict__ bt_ih, const float* __restrict__ bt_hh,
                      const float* __restrict__ wp, const float* __restrict__ F1,
                      float* __restrict__ wsf)
{
  int n = blockIdx.x*256 + threadIdx.x;
  if (n < 98560){   // W bf16 [o 320][k 616], RNE, zero-padded
    int o=n/308, c=n%308;
    int k0=2*c, k1=2*c+1;
    float v0 = (o<300 && k0<600)? wp[o*600+k0] : 0.f;
    float v1 = (o<300 && k1<600)? wp[o*600+k1] : 0.f;
    ((unsigned*)wsf)[OFF_WBF + n] = ((unsigned)f2usr(v1)<<16) | f2usr(v0);
    return;
  }
  n -= 98560;
  if (n < 99000){
    int h=n%300; int q=n/300; int g=q%3; int m=q/3; int i=m%11; int k=m/11;
    int G = h + (g==0?0:(g==1?600:900));
    wsf[OFF_WIHP+n] = Wih[(k*1200 + G)*11 + i]; return;
  }
  n -= 99000;
  if (n < 9000){
    int h=n%300; int q=n/300; int g=q%3, k=q/3;
    int G = h + (g==0?0:(g==1?600:900));
    wsf[OFF_BCP+n] = b_ih[k*1200+G] + b_hh[k*1200+G]; return;
  }
  n -= 9000;
  if (n < 900){
    int h=n%300, g=n/300;
    int G = h + (g==0?0:(g==1?600:900));
    wsf[OFF_BTP+n] = bt_ih[G]+bt_hh[G]; return;
  }
  n -= 900;
  if (n < 3600){
    int h=n%300; int q=n/300; int g=q%3, e=q/3;
    int G = h + (g==0?0:(g==1?600:900));
    wsf[OFF_WTP+n] = Wt[G*4+e]; return;
  }
  n -= 3600;
  if (n < 76800){   // F1 packed bf16x2: lane j-tiles {lane,64+lane,128+lane,192+lane}
    int q=n%2; int r=n/2; int lane=r%64; int h=r/64;
    int j0 = q*128 + lane, j1 = q*128 + 64 + lane;
    float v0 = (j0<200)? F1[h*200+j0] : 0.f;
    float v1 = (j1<200)? F1[h*200+j1] : 0.f;
    unsigned u = (__float_as_uint(v1)&0xffff0000u) | (__float_as_uint(v0)>>16);
    ((unsigned*)wsf)[OFF_F1P + n] = u; return;
  }
}

__global__ void kprep2(const float* __restrict__ DisM, float* __restrict__ wsf){
  if (threadIdx.x==0 && blockIdx.x==0){
    float m = DisM[0];
    for (int k=1;k<10;k++) m = fmaxf(m, DisM[k]);
    float e[10]; float s=0.f;
    for (int k=0;k<10;k++){ e[k]=__expf(DisM[k]-m); s+=e[k]; }
    float inv=1.0f/s; float sw=0.f;
    for (int k=0;k<10;k++){ float v=e[k]*inv; wsf[OFF_WA+k]=v; sw+=v; }
    wsf[OFF_SWA]=sw;
  }
}

extern "C" void kernel_launch(void* const* d_in, const int* in_sizes, int n_in,
                              void* d_out, int out_size, void* d_ws, size_t ws_size,
                              hipStream_t stream)
{
  const float* li     = (const float*)d_in[0];
  const float* labels = (const float*)d_in[1];
  const float* exs    = (const float*)d_in[2];
  const float* DisM   = (const float*)d_in[3];
  const float* AngleM = (const float*)d_in[4];
  const float* Wih    = (const float*)d_in[5];
  const float* b_ih   = (const float*)d_in[6];
  const float* b_hh   = (const float*)d_in[7];
  const float* Wt     = (const float*)d_in[8];
  const float* bt_ih  = (const float*)d_in[9];
  const float* bt_hh  = (const float*)d_in[10];
  const float* wp     = (const float*)d_in[11];
  const float* bp     = (const float*)d_in[12];
  const float* F1     = (const float*)d_in[13];
  const float* b1     = (const float*)d_in[14];
  const float* F2     = (const float*)d_in[15];
  const float* b2     = (const float*)d_in[16];
  const float* ff     = (const float*)d_in[17];
  const float* bff    = (const float*)d_in[18];
  const float* fuse1  = (const float*)d_in[19];
  const float* biasf  = (const float*)d_in[20];
  const float* Wout   = (const float*)d_in[21];
  const float* biasout= (const float*)d_in[22];
  const float* a      = (const float*)d_in[23];
  float* wsf = (float*)d_ws;
  float* outp = (float*)d_out;
  unsigned* con1u = (unsigned*)((char*)d_ws + CON1_BYTE);

  if (ws_size < WS_MIN_BYTES) return;  // proven available (PATH1 ran in R4)

  kprep<<<dim3(1125), dim3(256), 0, stream>>>(Wih,b_ih,b_hh,Wt,bt_ih,bt_hh,wp,F1,wsf);
  kprep2<<<dim3(1), dim3(64), 0, stream>>>(DisM, wsf);
  kern_con0  <<<dim3(128),     NTHR, 0, stream>>>(li, wsf, con1u);
  kern_wpmfma<<<dim3(128, 31), NTHR, 0, stream>>>(li, wsf, bp, con1u);
  kern_attn  <<<dim3(128, 32), NTHR, 0, stream>>>(li, exs, AngleM, b1, F2, b2, wsf, con1u);
  kern_final <<<dim3(128, 32), NTHR, 0, stream>>>(li, ff, bff, fuse1, biasf, Wout, biasout, a,
                                                  wsf, con1u, outp);
  kernC<<<dim3(64), dim3(256), 0, stream>>>(labels, outp);
}

// Round 6
// 1070.094 us; speedup vs baseline: 7.6314x; 1.3146x over previous
//
#include <hip/hip_runtime.h>
#include <hip/hip_bf16.h>

// GCLSTM: B=512, T=32, H=300, K=10. f32 in/out.
// R6: one fused kernel per (t, b-tile): cells(t, t-1) -> wp-MFMA -> con1^T in LDS
// as hcat[n 48][608] (cols 0-300 con1^T, 300-600 htarget, 600 = 1.0 bias col)
// -> F1-MFMA (bias via row 600 of swizzled F1) -> wdyn reduce -> softmax -> sm.
// con1 tile stored [t][btile][n 40][o 300] bf16 for kern_final.
// Both GEMMs use pre-swizzled coalesced fragment layouts in ws.

#define TB 4
#define NTHR 320
#define KP 616

// ws layout (u32 slots)
#define OFF_SM    0         // softmax [32][10][512] f32          163840
#define OFF_WBF2  163840    // wp A-frags [mt19][ks19][lane64][4]  92416
#define OFF_F1S   256256    // F1 B-frags [nt13][ks19][lane64][4]  63232
#define OFF_WIHP  319488    // ((k*11+i)*3+g)*300+h f32            99000
#define OFF_BCP   418488    // (k*3+g)*300+h f32                    9000
#define OFF_BTP   427488    // g*300+h f32                           900
#define OFF_WTP   428388    // (e*3+g)*300+h f32                    3600
#define OFF_WA    431988    // softmax(DisM) f32                      10
#define OFF_SWA   431998    // sum(wA) f32                             1
#define BASE_U32  432000
#define CON1_BYTE ((size_t)BASE_U32 * 4)                  // 1,728,000
#define WS_MIN_BYTES (CON1_BYTE + (size_t)98304000)       // 100,032,000 (< proven 100,436,608)

typedef __attribute__((ext_vector_type(8))) short s16x8;
typedef __attribute__((ext_vector_type(4))) float f32x4;
typedef unsigned short u16;

__device__ __forceinline__ float sigf(float x){ return 1.0f/(1.0f+__expf(-x)); }
__device__ __forceinline__ float tanhf_(float x){ return 1.0f - 2.0f/(__expf(2.0f*x)+1.0f); }
__device__ __forceinline__ float bfu(u16 u){ return __uint_as_float(((unsigned)u)<<16); }
__device__ __forceinline__ u16 f2usr(float f){   // RNE bf16
  __hip_bfloat16 h = __float2bfloat16(f);
  return *(u16*)&h;
}

// ================= fused per-(t, b-tile) kernel =================
__global__ __launch_bounds__(NTHR,2) void kern_main(
    const float* __restrict__ li, const float* __restrict__ exs,
    const float* __restrict__ AngleM, const float* __restrict__ bp,
    const float* __restrict__ F2, const float* __restrict__ b2,
    const float* wsf, unsigned* __restrict__ con1u, float* smg)
{
  __shared__ __align__(16) u16 cct[48][KP];   // 59,136 B: cells B-matrix, then hcat
  __shared__ float xs[2][TB][11][10];         //  3,520
  __shared__ float xse[TB][2][10];            //    320
  __shared__ float exss[TB][4];               //     64
  __shared__ float wdP[5][48];                //    960
  __shared__ float wdL[48];                   //    192   (total 64,192 B)
  const int tid = threadIdx.x;
  const int t = blockIdx.y, bt = blockIdx.x, b0 = bt*TB;
  const int w = tid>>6, lane = tid&63, lo = lane&15, qd = lane>>4;

  // ---- P0: stage inputs; zero cells K-pad cols [600,608) rows 0..39 ----
  for (int p=tid; p<2*TB*110; p+=NTHR){
    int half=p/440, r=p%440, b=r/110, q=r%110, i=q/10, k=q%10;
    int tp = half ? (t>0? t-1 : 0) : t;
    xs[half][b][i][k] = li[(((b0+b)*32+tp)*28+i)*10+k];
  }
  for (int p=tid;p<TB*20;p+=NTHR){
    int b=p/20, r=p%20, rr=r/10, k=r%10;
    xse[b][rr][k] = li[(((b0+b)*32+t)*28 + (rr?10:8))*10 + k];
  }
  for (int p=tid;p<TB*4;p+=NTHR){
    int b=p/4, e=p%4;
    exss[b][e] = exs[((b0+b)*32+t)*4+e];
  }
  for (int p=tid; p<40*4; p+=NTHR){
    int n=p/4, c=p%4;
    ((unsigned*)&cct[n][600])[c] = 0u;
  }
  __syncthreads();

  // ---- P1: cells for t (half 0) and t-1 (half 1), W loaded once per (k,h) ----
  const int nh = (t==0)?1:2;
  for (int p=tid; p<3000; p+=NTHR){
    int k=p/300, h=p%300;
    const float* W = wsf + OFF_WIHP + k*9900 + h;
    float wi[11], wg[11], wo[11];
    #pragma unroll
    for (int i=0;i<11;i++){
      wi[i]=W[(i*3+0)*300]; wg[i]=W[(i*3+1)*300]; wo[i]=W[(i*3+2)*300];
    }
    float bi = wsf[OFF_BCP+(k*3+0)*300+h];
    float bg2= wsf[OFF_BCP+(k*3+1)*300+h];
    float bo = wsf[OFF_BCP+(k*3+2)*300+h];
    for (int half=0; half<nh; half++){
      #pragma unroll
      for (int b=0;b<TB;b++){
        float ai=0.f, ag=0.f, ao=0.f;
        #pragma unroll
        for (int i=0;i<11;i++){
          float xv = xs[half][b][i][k];
          ai += wi[i]*xv; ag += wg[i]*xv; ao += wo[i]*xv;
        }
        float hv = sigf(ao+bo) * tanhf_( sigf(ai+bi) * tanhf_(ag+bg2) );
        cct[b*10+k][h+300*half] = f2usr(hv);
      }
    }
  }
  __syncthreads();

  // ---- P2: wp-MFMA  D[o 304][n 48] = W[304x608] @ cct[608x48] ----
  f32x4 acc[4][3];
  #pragma unroll
  for (int i=0;i<4;i++)
    #pragma unroll
    for (int nt=0;nt<3;nt++) acc[i][nt] = (f32x4){0.f,0.f,0.f,0.f};
  if (t>0){
    const u16* wbfA = (const u16*)((const unsigned*)wsf + OFF_WBF2);
    for (int ks=0; ks<19; ks++){
      const int kb = ks*32 + qd*8;
      s16x8 Bv[3];
      #pragma unroll
      for (int nt=0;nt<3;nt++)
        Bv[nt] = *(const s16x8*)&cct[nt*16+lo][kb];
      #pragma unroll
      for (int i=0;i<4;i++){
        int mt = w*4+i;
        if (mt<19){
          s16x8 Av = *(const s16x8*)(wbfA + ((size_t)(mt*19+ks)*64 + lane)*8);
          #pragma unroll
          for (int nt=0;nt<3;nt++)
            acc[i][nt] = __builtin_amdgcn_mfma_f32_16x16x32_bf16(Av, Bv[nt], acc[i][nt], 0,0,0);
        }
      }
    }
  }
  __syncthreads();   // all B-reads of cct done before hcat overwrite

  // ---- P2b (t>0): epilogue transpose: cct[n][o] = relu(D+bp) bf16, o<300 ----
  if (t>0){
    #pragma unroll
    for (int i=0;i<4;i++){
      int mt = w*4+i;
      if (mt<19 && (mt<18 || qd<3)){   // skip o in [300,304)
        int ob = mt*16 + qd*4;
        float p0=bp[ob], p1=bp[ob+1], p2=bp[ob+2], p3=bp[ob+3];
        #pragma unroll
        for (int nt=0;nt<3;nt++){
          int n = nt*16+lo;
          float v0=acc[i][nt][0]+p0, v1=acc[i][nt][1]+p1,
                v2=acc[i][nt][2]+p2, v3=acc[i][nt][3]+p3;
          unsigned w0 = ((unsigned)f2usr(v1>0.f?v1:0.f)<<16) | f2usr(v0>0.f?v0:0.f);
          unsigned w1 = ((unsigned)f2usr(v3>0.f?v3:0.f)<<16) | f2usr(v2>0.f?v2:0.f);
          *(unsigned*)&cct[n][ob]   = w0;
          *(unsigned*)&cct[n][ob+2] = w1;
        }
      }
    }
  }
  // ---- P3: htarget -> hcat cols [300,600); col 600 = 1.0; cols 601..607 = 0 ----
  for (int p=tid; p<TB*300; p+=NTHR){
    int b=p/300, o=p%300;
    float ai=0.f, ag=0.f, ao=0.f;
    #pragma unroll
    for (int e=0;e<4;e++){
      float xv = exss[b][e];
      ai += wsf[OFF_WTP+(e*3+0)*300+o]*xv;
      ag += wsf[OFF_WTP+(e*3+1)*300+o]*xv;
      ao += wsf[OFF_WTP+(e*3+2)*300+o]*xv;
    }
    ai += wsf[OFF_BTP+o]; ag += wsf[OFF_BTP+300+o]; ao += wsf[OFF_BTP+600+o];
    u16 u = f2usr( sigf(ao)*tanhf_(sigf(ai)*tanhf_(ag)) );
    #pragma unroll
    for (int k=0;k<10;k++) cct[b*10+k][300+o] = u;
  }
  for (int p=tid; p<48*4; p+=NTHR){
    int n=p/4, c=p%4;
    ((unsigned*)&cct[n][600])[c] = (c==0)? 0x00003f80u : 0u;   // cols 600,601 = {1.0, 0}
  }
  __syncthreads();

  // ---- P5: store con1 tile [n 40][o 300] coalesced (overlaps with P4 issue) ----
  for (int p=tid; p<6000; p+=NTHR){
    int n=p/150, op=p%150;
    con1u[ ((size_t)(t*128+bt)*40 + n)*150 + op ] = *(const unsigned*)&cct[n][2*op];
  }

  // ---- P4: F1-MFMA  fc1[n 48][j 208] = hcat[48x608] @ F1[608x208] ----
  const int ntbeg = (w<3)? w*3 : 9+(w-3)*2;
  const int ntn   = (w<3)? 3 : 2;
  f32x4 acc2[3][3];
  #pragma unroll
  for (int mt=0;mt<3;mt++)
    #pragma unroll
    for (int j=0;j<3;j++) acc2[mt][j] = (f32x4){0.f,0.f,0.f,0.f};
  {
    const u16* f1s = (const u16*)((const unsigned*)wsf + OFF_F1S);
    for (int ks=0; ks<19; ks++){
      const int kb = ks*32 + qd*8;
      s16x8 Am[3];
      #pragma unroll
      for (int mt=0;mt<3;mt++)
        Am[mt] = *(const s16x8*)&cct[mt*16+lo][kb];
      #pragma unroll
      for (int j=0;j<3;j++){
        if (j<ntn){
          int nt = ntbeg+j;
          s16x8 Bf = *(const s16x8*)(f1s + ((size_t)(nt*19+ks)*64 + lane)*8);
          #pragma unroll
          for (int mt=0;mt<3;mt++)
            acc2[mt][j] = __builtin_amdgcn_mfma_f32_16x16x32_bf16(Am[mt], Bf, acc2[mt][j], 0,0,0);
        }
      }
    }
  }
  // wdyn partials: relu(fc1)*F2, sum over this wave's j-cols, reduce 16 lanes/quad
  {
    float f2c[3];
    #pragma unroll
    for (int j=0;j<3;j++){
      int jj = (ntbeg+j)*16+lo;
      f2c[j] = (j<ntn && jj<200)? F2[jj] : 0.f;
    }
    #pragma unroll
    for (int mt=0;mt<3;mt++)
      #pragma unroll
      for (int r=0;r<4;r++){
        float s = 0.f;
        #pragma unroll
        for (int j=0;j<3;j++){
          float v = acc2[mt][j][r];
          s += (v>0.f? v:0.f) * f2c[j];
        }
        s += __shfl_xor(s,1,64); s += __shfl_xor(s,2,64);
        s += __shfl_xor(s,4,64); s += __shfl_xor(s,8,64);
        if (lo==0) wdP[w][mt*16+qd*4+r] = s;
      }
  }
  __syncthreads();
  if (tid<40){
    int n=tid, b=n/10, k=n%10;
    float v = wdP[0][n]+wdP[1][n]+wdP[2][n]+wdP[3][n]+wdP[4][n];
    float ang = fabsf(xse[b][1][k]-AngleM[k]) * (1.0f/360.0f);
    v += xse[b][0][k]*F2[200] + ang*F2[201] + b2[0];
    wdL[n] = v>0.f? v : 0.f;
  }
  __syncthreads();
  if (tid<TB){
    int b=tid;
    float m = wdL[b*10];
    #pragma unroll
    for (int k=1;k<10;k++) m = fmaxf(m, wdL[b*10+k]);
    float e[10]; float s=0.f;
    #pragma unroll
    for (int k=0;k<10;k++){ e[k]=__expf(wdL[b*10+k]-m); s+=e[k]; }
    float inv = 1.0f/s;
    #pragma unroll
    for (int k=0;k<10;k++) smg[t*5120 + k*512 + b0+b] = e[k]*inv;
  }
}

// ================= final: gather scramble, fuse, preds =================
__global__ __launch_bounds__(NTHR,2) void kern_final(
    const float* __restrict__ li, const float* __restrict__ ff,
    const float* __restrict__ bff, const float* __restrict__ fuse1,
    const float* __restrict__ biasf, const float* __restrict__ Wout,
    const float* __restrict__ biasout, const float* __restrict__ a,
    const float* wsf, const unsigned* __restrict__ con1u,
    float* __restrict__ outp)
{
  __shared__ unsigned conTu[40][152];   // [n][o-pairs]; u16 view stride 304
  __shared__ float xs17[TB][17][10];
  __shared__ float cats[TB][300];
  __shared__ float wa3s[TB][10];
  __shared__ float dss[TB][17];
  __shared__ float wAs[10];
  const int tid=threadIdx.x, t=blockIdx.y, bt=blockIdx.x, b0=bt*TB;
  for (int p=tid;p<TB*170;p+=NTHR){
    int b=p/170, r=p%170, f=r/10, k=r%10;
    xs17[b][f][k] = li[(((b0+b)*32+t)*28 + 11+f)*10 + k];
  }
  if (tid<10) wAs[tid] = wsf[OFF_WA+tid];
  for (int p=tid;p<6000;p+=NTHR){
    int n=p/150, op=p%150;
    conTu[n][op] = con1u[ ((size_t)(t*128+bt)*40 + n)*150 + op ];
  }
  __syncthreads();
  for (int p=tid;p<TB*10;p+=NTHR){
    int b=p/10, k=p%10;
    int g = (b0+b)*10+k;   // flat-reshape scramble of the [10,512] softmax matrix
    wa3s[b][k] = wsf[OFF_SM + t*5120 + (g>>9)*512 + (g&511)];
  }
  for (int p=tid;p<TB*17;p+=NTHR){
    int b=p/17, f=p%17; float s=0.f;
    #pragma unroll
    for (int k=0;k<10;k++) s += xs17[b][f][k]*wAs[k];
    dss[b][f]=s;
  }
  __syncthreads();
  const u16* conT = (const u16*)conTu;
  for (int p=tid;p<TB*300;p+=NTHR){
    int b=p/300, h=p%300;
    float s=0.f;
    #pragma unroll
    for (int k=0;k<10;k++)
      s += bfu(conT[(b*10+k)*304 + h]) * wa3s[b][k];
    cats[b][h]=s;
  }
  __syncthreads();
  const int w = tid>>6, lane = tid&63;
  if (w<TB){
    const int b=w, bg=b0+b;
    const float aa = a[0], swa = wsf[OFF_SWA];
    const int o1 = lane;
    const bool o2v = lane<36;
    const int o2 = o2v ? (64+lane) : 99;
    float fu1 = biasf[o1], fu2 = biasf[o2];
    for (int h=0;h<300;h++){
      float cv = cats[b][h];
      fu1 += cv*fuse1[h*100+o1];
      fu2 += cv*fuse1[h*100+o2];
    }
    float fd1 = bff[o1]*swa, fd2 = bff[o2]*swa;
    #pragma unroll
    for (int f=0;f<17;f++){
      float dv = dss[b][f];
      fd1 += ff[o1*17+f]*dv;
      fd2 += ff[o2*17+f]*dv;
    }
    float v = (aa*fu1+(1.f-aa)*fd1)*Wout[o1];
    if (o2v) v += (aa*fu2+(1.f-aa)*fd2)*Wout[o2];
    #pragma unroll
    for (int off=32;off>=1;off>>=1) v += __shfl_xor(v,off,64);
    if (lane==0) outp[t*512+bg] = v + biasout[0];
  }
}

__global__ void kernC(const float* __restrict__ labels, float* __restrict__ outp){
  int p = blockIdx.x*256 + threadIdx.x;
  if (p < 16384){
    int t=p>>9, b=p&511;
    outp[16384+p] = labels[b*32+t];
  }
}

// ================= weight prep =================
__global__ void kprep(const float* __restrict__ Wih, const float* __restrict__ b_ih,
                      const float* __restrict__ b_hh, const float* __restrict__ Wt,
                      const float* __restrict__ bt_ih, const float* __restrict__ bt_hh,
                      const float* __restrict__ wp, const float* __restrict__ F1,
                      const float* __restrict__ b1, float* __restrict__ wsf)
{
  int n = blockIdx.x*256 + threadIdx.x;
  if (n < 92416){   // wp A-frags: [mt][ks][lane][4 u32]; A[m][k], m=mt*16+lo, k=ks*32+qd*8+j
    int jp=n&3, lane=(n>>2)&63, rest=n>>8;
    int ks=rest%19, mt=rest/19;
    int m = mt*16 + (lane&15);
    int k = ks*32 + (lane>>4)*8 + 2*jp;
    float v0 = (m<300 && k  <600)? wp[m*600+k  ] : 0.f;
    float v1 = (m<300 && k+1<600)? wp[m*600+k+1] : 0.f;
    ((unsigned*)wsf)[OFF_WBF2+n] = ((unsigned)f2usr(v1)<<16) | f2usr(v0);
    return;
  }
  n -= 92416;
  if (n < 63232){   // F1 B-frags: [nt][ks][lane][4]; B[k][j], j=nt*16+lo; row 600 = b1
    int jp=n&3, lane=(n>>2)&63, rest=n>>8;
    int ks=rest%19, nt=rest/19;
    int col = nt*16 + (lane&15);
    int k = ks*32 + (lane>>4)*8 + 2*jp;
    float v0=0.f, v1=0.f;
    if (col<200){
      v0 = (k  <600)? F1[k*200+col]     : (k  ==600? b1[col] : 0.f);
      v1 = (k+1<600)? F1[(k+1)*200+col] : (k+1==600? b1[col] : 0.f);
    }
    ((unsigned*)wsf)[OFF_F1S+n] = ((unsigned)f2usr(v1)<<16) | f2usr(v0);
    return;
  }
  n -= 63232;
  if (n < 99000){
    int h=n%300; int q=n/300; int g=q%3; int m=q/3; int i=m%11; int k=m/11;
    int G = h + (g==0?0:(g==1?600:900));
    wsf[OFF_WIHP+n] = Wih[(k*1200 + G)*11 + i]; return;
  }
  n -= 99000;
  if (n < 9000){
    int h=n%300; int q=n/300; int g=q%3, k=q/3;
    int G = h + (g==0?0:(g==1?600:900));
    wsf[OFF_BCP+n] = b_ih[k*1200+G] + b_hh[k*1200+G]; return;
  }
  n -= 9000;
  if (n < 900){
    int h=n%300, g=n/300;
    int G = h + (g==0?0:(g==1?600:900));
    wsf[OFF_BTP+n] = bt_ih[G]+bt_hh[G]; return;
  }
  n -= 900;
  if (n < 3600){
    int h=n%300; int q=n/300; int g=q%3, e=q/3;
    int G = h + (g==0?0:(g==1?600:900));
    wsf[OFF_WTP+n] = Wt[G*4+e]; return;
  }
}

__global__ void kprep2(const float* __restrict__ DisM, float* __restrict__ wsf){
  if (threadIdx.x==0 && blockIdx.x==0){
    float m = DisM[0];
    for (int k=1;k<10;k++) m = fmaxf(m, DisM[k]);
    float e[10]; float s=0.f;
    for (int k=0;k<10;k++){ e[k]=__expf(DisM[k]-m); s+=e[k]; }
    float inv=1.0f/s; float sw=0.f;
    for (int k=0;k<10;k++){ float v=e[k]*inv; wsf[OFF_WA+k]=v; sw+=v; }
    wsf[OFF_SWA]=sw;
  }
}

extern "C" void kernel_launch(void* const* d_in, const int* in_sizes, int n_in,
                              void* d_out, int out_size, void* d_ws, size_t ws_size,
                              hipStream_t stream)
{
  const float* li     = (const float*)d_in[0];
  const float* labels = (const float*)d_in[1];
  const float* exs    = (const float*)d_in[2];
  const float* DisM   = (const float*)d_in[3];
  const float* AngleM = (const float*)d_in[4];
  const float* Wih    = (const float*)d_in[5];
  const float* b_ih   = (const float*)d_in[6];
  const float* b_hh   = (const float*)d_in[7];
  const float* Wt     = (const float*)d_in[8];
  const float* bt_ih  = (const float*)d_in[9];
  const float* bt_hh  = (const float*)d_in[10];
  const float* wp     = (const float*)d_in[11];
  const float* bp     = (const float*)d_in[12];
  const float* F1     = (const float*)d_in[13];
  const float* b1     = (const float*)d_in[14];
  const float* F2     = (const float*)d_in[15];
  const float* b2     = (const float*)d_in[16];
  const float* ff     = (const float*)d_in[17];
  const float* bff    = (const float*)d_in[18];
  const float* fuse1  = (const float*)d_in[19];
  const float* biasf  = (const float*)d_in[20];
  const float* Wout   = (const float*)d_in[21];
  const float* biasout= (const float*)d_in[22];
  const float* a      = (const float*)d_in[23];
  float* wsf = (float*)d_ws;
  float* outp = (float*)d_out;
  unsigned* con1u = (unsigned*)((char*)d_ws + CON1_BYTE);

  if (ws_size < WS_MIN_BYTES) return;  // proven available (R4 PATH1 ran)

  kprep<<<dim3(1048), dim3(256), 0, stream>>>(Wih,b_ih,b_hh,Wt,bt_ih,bt_hh,wp,F1,b1,wsf);
  kprep2<<<dim3(1), dim3(64), 0, stream>>>(DisM, wsf);
  kern_main <<<dim3(128,32), NTHR, 0, stream>>>(li, exs, AngleM, bp, F2, b2,
                                                wsf, con1u, wsf + OFF_SM);
  kern_final<<<dim3(128,32), NTHR, 0, stream>>>(li, ff, bff, fuse1, biasf, Wout, biasout, a,
                                                wsf, con1u, outp);
  kernC<<<dim3(64), dim3(256), 0, stream>>>(labels, outp);
}

// Round 7
// 827.922 us; speedup vs baseline: 9.8636x; 1.2925x over previous
//
#include <hip/hip_runtime.h>
#include <hip/hip_bf16.h>

// GCLSTM: B=512, T=32, H=300, K=10. f32 in/out.
// R7 = R6 structure with 10-wave blocks (latency/occupancy fix):
// kern_main per (t,btile): cells(t,t-1) -> wp-MFMA -> con1^T in LDS as
// hcat[48][608] -> F1-MFMA (bias row trick) -> wdyn -> softmax -> sm.
// kern_final: gather scramble, cats, fuse (8-wave split), preds.

#define TB 4
#define NTHR 640          // 10 waves
#define NW 10
#define KP 616

// ws layout (u32 slots)
#define OFF_SM    0         // softmax [32][10][512] f32          163840
#define OFF_WBF2  163840    // wp A-frags [mt19][ks19][lane64][4]  92416
#define OFF_F1S   256256    // F1 B-frags [nt13][ks19][lane64][4]  63232
#define OFF_WIHP  319488    // ((k*11+i)*3+g)*300+h f32            99000
#define OFF_BCP   418488    // (k*3+g)*300+h f32                    9000
#define OFF_BTP   427488    // g*300+h f32                           900
#define OFF_WTP   428388    // (e*3+g)*300+h f32                    3600
#define OFF_WA    431988    // softmax(DisM) f32                      10
#define OFF_SWA   431998    // sum(wA) f32                             1
#define BASE_U32  432000
#define CON1_BYTE ((size_t)BASE_U32 * 4)                  // 1,728,000
#define WS_MIN_BYTES (CON1_BYTE + (size_t)98304000)       // 100,032,000 (< proven 100,436,608)

typedef __attribute__((ext_vector_type(8))) short s16x8;
typedef __attribute__((ext_vector_type(4))) float f32x4;
typedef unsigned short u16;

__device__ __forceinline__ float sigf(float x){ return 1.0f/(1.0f+__expf(-x)); }
__device__ __forceinline__ float tanhf_(float x){ return 1.0f - 2.0f/(__expf(2.0f*x)+1.0f); }
__device__ __forceinline__ float bfu(u16 u){ return __uint_as_float(((unsigned)u)<<16); }
__device__ __forceinline__ u16 f2usr(float f){   // RNE bf16
  __hip_bfloat16 h = __float2bfloat16(f);
  return *(u16*)&h;
}

// ================= fused per-(t, b-tile) kernel, 10 waves =================
__global__ __launch_bounds__(NTHR,2) void kern_main(
    const float* __restrict__ li, const float* __restrict__ exs,
    const float* __restrict__ AngleM, const float* __restrict__ bp,
    const float* __restrict__ F2, const float* __restrict__ b2,
    const float* wsf, unsigned* __restrict__ con1u, float* smg)
{
  __shared__ __align__(16) u16 cct[48][KP];   // 59,136 B
  __shared__ float xs[2][TB][11][10];         //  3,520
  __shared__ float xse[TB][2][10];            //    320
  __shared__ float exss[TB][4];               //     64
  __shared__ float wdP[NW][48];               //  1,920
  __shared__ float wdL[48];                   //    192  (total 65,152 <= 65,536)
  const int tid = threadIdx.x;
  const int t = blockIdx.y, bt = blockIdx.x, b0 = bt*TB;
  const int w = tid>>6, lane = tid&63, lo = lane&15, qd = lane>>4;

  // ---- P0: stage inputs; zero cells K-pad cols [600,608) rows 0..39 ----
  for (int p=tid; p<2*TB*110; p+=NTHR){
    int half=p/440, r=p%440, b=r/110, q=r%110, i=q/10, k=q%10;
    int tp = half ? (t>0? t-1 : 0) : t;
    xs[half][b][i][k] = li[(((b0+b)*32+tp)*28+i)*10+k];
  }
  for (int p=tid;p<TB*20;p+=NTHR){
    int b=p/20, r=p%20, rr=r/10, k=r%10;
    xse[b][rr][k] = li[(((b0+b)*32+t)*28 + (rr?10:8))*10 + k];
  }
  for (int p=tid;p<TB*4;p+=NTHR){
    int b=p/4, e=p%4;
    exss[b][e] = exs[((b0+b)*32+t)*4+e];
  }
  for (int p=tid; p<40*4; p+=NTHR){
    int n=p/4, c=p%4;
    ((unsigned*)&cct[n][600])[c] = 0u;
  }
  __syncthreads();

  // ---- P1: cells for t (half 0) and t-1 (half 1), W loaded once per (k,h) ----
  const int nh = (t==0)?1:2;
  for (int p=tid; p<3000; p+=NTHR){
    int k=p/300, h=p%300;
    const float* W = wsf + OFF_WIHP + k*9900 + h;
    float wi[11], wg[11], wo[11];
    #pragma unroll
    for (int i=0;i<11;i++){
      wi[i]=W[(i*3+0)*300]; wg[i]=W[(i*3+1)*300]; wo[i]=W[(i*3+2)*300];
    }
    float bi = wsf[OFF_BCP+(k*3+0)*300+h];
    float bg2= wsf[OFF_BCP+(k*3+1)*300+h];
    float bo = wsf[OFF_BCP+(k*3+2)*300+h];
    for (int half=0; half<nh; half++){
      #pragma unroll
      for (int b=0;b<TB;b++){
        float ai=0.f, ag=0.f, ao=0.f;
        #pragma unroll
        for (int i=0;i<11;i++){
          float xv = xs[half][b][i][k];
          ai += wi[i]*xv; ag += wg[i]*xv; ao += wo[i]*xv;
        }
        float hv = sigf(ao+bo) * tanhf_( sigf(ai+bi) * tanhf_(ag+bg2) );
        cct[b*10+k][h+300*half] = f2usr(hv);
      }
    }
  }
  __syncthreads();

  // ---- P2: wp-MFMA  D[o 304][n 48] = W[304x608] @ cct[608x48]; 2 Mtiles/wave ----
  f32x4 acc[2][3];
  #pragma unroll
  for (int i=0;i<2;i++)
    #pragma unroll
    for (int nt=0;nt<3;nt++) acc[i][nt] = (f32x4){0.f,0.f,0.f,0.f};
  if (t>0){
    const u16* wbfA = (const u16*)((const unsigned*)wsf + OFF_WBF2);
    for (int ks=0; ks<19; ks++){
      const int kb = ks*32 + qd*8;
      s16x8 Bv[3];
      #pragma unroll
      for (int nt=0;nt<3;nt++)
        Bv[nt] = *(const s16x8*)&cct[nt*16+lo][kb];
      #pragma unroll
      for (int i=0;i<2;i++){
        int mt = w*2+i;
        if (mt<19){
          s16x8 Av = *(const s16x8*)(wbfA + ((size_t)(mt*19+ks)*64 + lane)*8);
          #pragma unroll
          for (int nt=0;nt<3;nt++)
            acc[i][nt] = __builtin_amdgcn_mfma_f32_16x16x32_bf16(Av, Bv[nt], acc[i][nt], 0,0,0);
        }
      }
    }
  }
  __syncthreads();   // all B-reads of cct done before hcat overwrite

  // ---- P2b (t>0): epilogue transpose: cct[n][o] = relu(D+bp) bf16, o<300 ----
  if (t>0){
    #pragma unroll
    for (int i=0;i<2;i++){
      int mt = w*2+i;
      if (mt<19 && (mt<18 || qd<3)){   // skip o in [300,304)
        int ob = mt*16 + qd*4;
        float p0=bp[ob], p1=bp[ob+1], p2=bp[ob+2], p3=bp[ob+3];
        #pragma unroll
        for (int nt=0;nt<3;nt++){
          int n = nt*16+lo;
          float v0=acc[i][nt][0]+p0, v1=acc[i][nt][1]+p1,
                v2=acc[i][nt][2]+p2, v3=acc[i][nt][3]+p3;
          unsigned w0 = ((unsigned)f2usr(v1>0.f?v1:0.f)<<16) | f2usr(v0>0.f?v0:0.f);
          unsigned w1 = ((unsigned)f2usr(v3>0.f?v3:0.f)<<16) | f2usr(v2>0.f?v2:0.f);
          *(unsigned*)&cct[n][ob]   = w0;
          *(unsigned*)&cct[n][ob+2] = w1;
        }
      }
    }
  }
  // ---- P3: htarget -> hcat cols [300,600); col 600 = 1.0 ----
  for (int p=tid; p<TB*300; p+=NTHR){
    int b=p/300, o=p%300;
    float ai=0.f, ag=0.f, ao=0.f;
    #pragma unroll
    for (int e=0;e<4;e++){
      float xv = exss[b][e];
      ai += wsf[OFF_WTP+(e*3+0)*300+o]*xv;
      ag += wsf[OFF_WTP+(e*3+1)*300+o]*xv;
      ao += wsf[OFF_WTP+(e*3+2)*300+o]*xv;
    }
    ai += wsf[OFF_BTP+o]; ag += wsf[OFF_BTP+300+o]; ao += wsf[OFF_BTP+600+o];
    u16 u = f2usr( sigf(ao)*tanhf_(sigf(ai)*tanhf_(ag)) );
    #pragma unroll
    for (int k=0;k<10;k++) cct[b*10+k][300+o] = u;
  }
  for (int p=tid; p<48*4; p+=NTHR){
    int n=p/4, c=p%4;
    ((unsigned*)&cct[n][600])[c] = (c==0)? 0x00003f80u : 0u;
  }
  __syncthreads();

  // ---- P5: store con1 tile [n 40][o 300] coalesced ----
  for (int p=tid; p<6000; p+=NTHR){
    int n=p/150, op=p%150;
    con1u[ ((size_t)(t*128+bt)*40 + n)*150 + op ] = *(const unsigned*)&cct[n][2*op];
  }

  // ---- P4: F1-MFMA  fc1[n 48][j 208] = hcat[48x608] @ F1[608x208]; nt in {w, w+10} ----
  f32x4 acc2[3][2];
  #pragma unroll
  for (int mt=0;mt<3;mt++)
    #pragma unroll
    for (int j=0;j<2;j++) acc2[mt][j] = (f32x4){0.f,0.f,0.f,0.f};
  {
    const u16* f1s = (const u16*)((const unsigned*)wsf + OFF_F1S);
    for (int ks=0; ks<19; ks++){
      const int kb = ks*32 + qd*8;
      s16x8 Am[3];
      #pragma unroll
      for (int mt=0;mt<3;mt++)
        Am[mt] = *(const s16x8*)&cct[mt*16+lo][kb];
      #pragma unroll
      for (int j=0;j<2;j++){
        int nt = w + j*NW;
        if (nt<13){
          s16x8 Bf = *(const s16x8*)(f1s + ((size_t)(nt*19+ks)*64 + lane)*8);
          #pragma unroll
          for (int mt=0;mt<3;mt++)
            acc2[mt][j] = __builtin_amdgcn_mfma_f32_16x16x32_bf16(Am[mt], Bf, acc2[mt][j], 0,0,0);
        }
      }
    }
  }
  // wdyn partials: relu(fc1)*F2, sum this wave's j-cols, reduce within quads
  {
    float f2c[2];
    #pragma unroll
    for (int j=0;j<2;j++){
      int nt = w + j*NW;
      int jj = nt*16+lo;
      f2c[j] = (nt<13 && jj<200)? F2[jj] : 0.f;
    }
    #pragma unroll
    for (int mt=0;mt<3;mt++)
      #pragma unroll
      for (int r=0;r<4;r++){
        float s = 0.f;
        #pragma unroll
        for (int j=0;j<2;j++){
          float v = acc2[mt][j][r];
          s += (v>0.f? v:0.f) * f2c[j];
        }
        s += __shfl_xor(s,1,64); s += __shfl_xor(s,2,64);
        s += __shfl_xor(s,4,64); s += __shfl_xor(s,8,64);
        if (lo==0) wdP[w][mt*16+qd*4+r] = s;
      }
  }
  __syncthreads();
  if (tid<40){
    int n=tid, b=n/10, k=n%10;
    float v = 0.f;
    #pragma unroll
    for (int ww=0;ww<NW;ww++) v += wdP[ww][n];
    float ang = fabsf(xse[b][1][k]-AngleM[k]) * (1.0f/360.0f);
    v += xse[b][0][k]*F2[200] + ang*F2[201] + b2[0];
    wdL[n] = v>0.f? v : 0.f;
  }
  __syncthreads();
  if (tid<TB){
    int b=tid;
    float m = wdL[b*10];
    #pragma unroll
    for (int k=1;k<10;k++) m = fmaxf(m, wdL[b*10+k]);
    float e[10]; float s=0.f;
    #pragma unroll
    for (int k=0;k<10;k++){ e[k]=__expf(wdL[b*10+k]-m); s+=e[k]; }
    float inv = 1.0f/s;
    #pragma unroll
    for (int k=0;k<10;k++) smg[t*5120 + k*512 + b0+b] = e[k]*inv;
  }
}

// ================= final: gather scramble, fuse, preds (10 waves) =================
__global__ __launch_bounds__(NTHR,3) void kern_final(
    const float* __restrict__ li, const float* __restrict__ ff,
    const float* __restrict__ bff, const float* __restrict__ fuse1,
    const float* __restrict__ biasf, const float* __restrict__ Wout,
    const float* __restrict__ biasout, const float* __restrict__ a,
    const float* wsf, const unsigned* __restrict__ con1u,
    float* __restrict__ outp)
{
  __shared__ unsigned conTu[40][152];   // [n][o-pairs]; u16 view stride 304
  __shared__ float xs17[TB][17][10];
  __shared__ float cats[TB][300];
  __shared__ float wa3s[TB][10];
  __shared__ float dss[TB][17];
  __shared__ float wAs[10];
  __shared__ float fup1[8][64], fup2[8][64];
  const int tid=threadIdx.x, t=blockIdx.y, bt=blockIdx.x, b0=bt*TB;
  for (int p=tid;p<TB*170;p+=NTHR){
    int b=p/170, r=p%170, f=r/10, k=r%10;
    xs17[b][f][k] = li[(((b0+b)*32+t)*28 + 11+f)*10 + k];
  }
  if (tid<10) wAs[tid] = wsf[OFF_WA+tid];
  for (int p=tid;p<6000;p+=NTHR){
    int n=p/150, op=p%150;
    conTu[n][op] = con1u[ ((size_t)(t*128+bt)*40 + n)*150 + op ];
  }
  __syncthreads();
  for (int p=tid;p<TB*10;p+=NTHR){
    int b=p/10, k=p%10;
    int g = (b0+b)*10+k;   // flat-reshape scramble of the [10,512] softmax matrix
    wa3s[b][k] = wsf[OFF_SM + t*5120 + (g>>9)*512 + (g&511)];
  }
  for (int p=tid;p<TB*17;p+=NTHR){
    int b=p/17, f=p%17; float s=0.f;
    #pragma unroll
    for (int k=0;k<10;k++) s += xs17[b][f][k]*wAs[k];
    dss[b][f]=s;
  }
  __syncthreads();
  const u16* conT = (const u16*)conTu;
  for (int p=tid;p<TB*300;p+=NTHR){
    int b=p/300, h=p%300;
    float s=0.f;
    #pragma unroll
    for (int k=0;k<10;k++)
      s += bfu(conT[(b*10+k)*304 + h]) * wa3s[b][k];
    cats[b][h]=s;
  }
  __syncthreads();
  const int w = tid>>6, lane = tid&63;
  const int o1 = lane;
  const bool o2v = lane<36;
  const int o2 = o2v ? (64+lane) : 99;
  if (w<8){   // fuse1 partials: wave = (b, half of h-range)
    int b=w>>1, half=w&1;
    float fu1 = half? 0.f : biasf[o1];
    float fu2 = half? 0.f : biasf[o2];
    const int hb = half*150;
    for (int h=hb; h<hb+150; h++){
      float cv = cats[b][h];
      fu1 += cv*fuse1[h*100+o1];
      fu2 += cv*fuse1[h*100+o2];
    }
    fup1[w][lane]=fu1; fup2[w][lane]=fu2;
  }
  __syncthreads();
  if (w<TB){
    const int b=w, bg=b0+b;
    const float aa = a[0], swa = wsf[OFF_SWA];
    float fu1 = fup1[2*b][lane] + fup1[2*b+1][lane];
    float fu2 = fup2[2*b][lane] + fup2[2*b+1][lane];
    float fd1 = bff[o1]*swa, fd2 = bff[o2]*swa;
    #pragma unroll
    for (int f=0;f<17;f++){
      float dv = dss[b][f];
      fd1 += ff[o1*17+f]*dv;
      fd2 += ff[o2*17+f]*dv;
    }
    float v = (aa*fu1+(1.f-aa)*fd1)*Wout[o1];
    if (o2v) v += (aa*fu2+(1.f-aa)*fd2)*Wout[o2];
    #pragma unroll
    for (int off=32;off>=1;off>>=1) v += __shfl_xor(v,off,64);
    if (lane==0) outp[t*512+bg] = v + biasout[0];
  }
}

__global__ void kernC(const float* __restrict__ labels, float* __restrict__ outp){
  int p = blockIdx.x*256 + threadIdx.x;
  if (p < 16384){
    int t=p>>9, b=p&511;
    outp[16384+p] = labels[b*32+t];
  }
}

// ================= weight prep =================
__global__ void kprep(const float* __restrict__ Wih, const float* __restrict__ b_ih,
                      const float* __restrict__ b_hh, const float* __restrict__ Wt,
                      const float* __restrict__ bt_ih, const float* __restrict__ bt_hh,
                      const float* __restrict__ wp, const float* __restrict__ F1,
                      const float* __restrict__ b1, float* __restrict__ wsf)
{
  int n = blockIdx.x*256 + threadIdx.x;
  if (n < 92416){   // wp A-frags: [mt][ks][lane][4 u32]
    int jp=n&3, lane=(n>>2)&63, rest=n>>8;
    int ks=rest%19, mt=rest/19;
    int m = mt*16 + (lane&15);
    int k = ks*32 + (lane>>4)*8 + 2*jp;
    float v0 = (m<300 && k  <600)? wp[m*600+k  ] : 0.f;
    float v1 = (m<300 && k+1<600)? wp[m*600+k+1] : 0.f;
    ((unsigned*)wsf)[OFF_WBF2+n] = ((unsigned)f2usr(v1)<<16) | f2usr(v0);
    return;
  }
  n -= 92416;
  if (n < 63232){   // F1 B-frags: [nt][ks][lane][4]; row 600 = b1
    int jp=n&3, lane=(n>>2)&63, rest=n>>8;
    int ks=rest%19, nt=rest/19;
    int col = nt*16 + (lane&15);
    int k = ks*32 + (lane>>4)*8 + 2*jp;
    float v0=0.f, v1=0.f;
    if (col<200){
      v0 = (k  <600)? F1[k*200+col]     : (k  ==600? b1[col] : 0.f);
      v1 = (k+1<600)? F1[(k+1)*200+col] : (k+1==600? b1[col] : 0.f);
    }
    ((unsigned*)wsf)[OFF_F1S+n] = ((unsigned)f2usr(v1)<<16) | f2usr(v0);
    return;
  }
  n -= 63232;
  if (n < 99000){
    int h=n%300; int q=n/300; int g=q%3; int m=q/3; int i=m%11; int k=m/11;
    int G = h + (g==0?0:(g==1?600:900));
    wsf[OFF_WIHP+n] = Wih[(k*1200 + G)*11 + i]; return;
  }
  n -= 99000;
  if (n < 9000){
    int h=n%300; int q=n/300; int g=q%3, k=q/3;
    int G = h + (g==0?0:(g==1?600:900));
    wsf[OFF_BCP+n] = b_ih[k*1200+G] + b_hh[k*1200+G]; return;
  }
  n -= 9000;
  if (n < 900){
    int h=n%300, g=n/300;
    int G = h + (g==0?0:(g==1?600:900));
    wsf[OFF_BTP+n] = bt_ih[G]+bt_hh[G]; return;
  }
  n -= 900;
  if (n < 3600){
    int h=n%300; int q=n/300; int g=q%3, e=q/3;
    int G = h + (g==0?0:(g==1?600:900));
    wsf[OFF_WTP+n] = Wt[G*4+e]; return;
  }
}

__global__ void kprep2(const float* __restrict__ DisM, float* __restrict__ wsf){
  if (threadIdx.x==0 && blockIdx.x==0){
    float m = DisM[0];
    for (int k=1;k<10;k++) m = fmaxf(m, DisM[k]);
    float e[10]; float s=0.f;
    for (int k=0;k<10;k++){ e[k]=__expf(DisM[k]-m); s+=e[k]; }
    float inv=1.0f/s; float sw=0.f;
    for (int k=0;k<10;k++){ float v=e[k]*inv; wsf[OFF_WA+k]=v; sw+=v; }
    wsf[OFF_SWA]=sw;
  }
}

extern "C" void kernel_launch(void* const* d_in, const int* in_sizes, int n_in,
                              void* d_out, int out_size, void* d_ws, size_t ws_size,
                              hipStream_t stream)
{
  const float* li     = (const float*)d_in[0];
  const float* labels = (const float*)d_in[1];
  const float* exs    = (const float*)d_in[2];
  const float* DisM   = (const float*)d_in[3];
  const float* AngleM = (const float*)d_in[4];
  const float* Wih    = (const float*)d_in[5];
  const float* b_ih   = (const float*)d_in[6];
  const float* b_hh   = (const float*)d_in[7];
  const float* Wt     = (const float*)d_in[8];
  const float* bt_ih  = (const float*)d_in[9];
  const float* bt_hh  = (const float*)d_in[10];
  const float* wp     = (const float*)d_in[11];
  const float* bp     = (const float*)d_in[12];
  const float* F1     = (const float*)d_in[13];
  const float* b1     = (const float*)d_in[14];
  const float* F2     = (const float*)d_in[15];
  const float* b2     = (const float*)d_in[16];
  const float* ff     = (const float*)d_in[17];
  const float* bff    = (const float*)d_in[18];
  const float* fuse1  = (const float*)d_in[19];
  const float* biasf  = (const float*)d_in[20];
  const float* Wout   = (const float*)d_in[21];
  const float* biasout= (const float*)d_in[22];
  const float* a      = (const float*)d_in[23];
  float* wsf = (float*)d_ws;
  float* outp = (float*)d_out;
  unsigned* con1u = (unsigned*)((char*)d_ws + CON1_BYTE);

  if (ws_size < WS_MIN_BYTES) return;  // proven available (R4 PATH1 ran)

  kprep<<<dim3(1048), dim3(256), 0, stream>>>(Wih,b_ih,b_hh,Wt,bt_ih,bt_hh,wp,F1,b1,wsf);
  kprep2<<<dim3(1), dim3(64), 0, stream>>>(DisM, wsf);
  kern_main <<<dim3(128,32), NTHR, 0, stream>>>(li, exs, AngleM, bp, F2, b2,
                                                wsf, con1u, wsf + OFF_SM);
  kern_final<<<dim3(128,32), NTHR, 0, stream>>>(li, ff, bff, fuse1, biasf, Wout, biasout, a,
                                                wsf, con1u, outp);
  kernC<<<dim3(64), dim3(256), 0, stream>>>(labels, outp);
}